// Round 1
// baseline (527.192 us; speedup 1.0000x reference)
//
#include <hip/hip_runtime.h>
#include <math.h>

#define N_NODES 10000
#define N_EDGES 160000
#define E2 (N_EDGES + N_NODES)
#define HIDDEN 128
#define NHEAD 4
#define NB 32
#define LN_EPS 1e-5f

// ---------------- CSR build ----------------
__global__ void k_init(int* counts, int* gstart, int* gend) {
    int i = blockIdx.x * blockDim.x + threadIdx.x;
    if (i < N_NODES) counts[i] = 1;             // self-loop
    if (i < NB) { gstart[i] = N_NODES; gend[i] = 0; }
}

__global__ void k_hist(const int* __restrict__ ei, int* counts) {
    int e = blockIdx.x * blockDim.x + threadIdx.x;
    if (e < N_EDGES) atomicAdd(&counts[ei[N_EDGES + e]], 1);
}

__global__ void k_scan(const int* __restrict__ counts, int* rowptr, int* cursor) {
    __shared__ int sums[1024];
    int t = threadIdx.x;
    const int per = 10;                          // 1024*10 >= 10000
    int base = t * per;
    int loc[per];
    int s = 0;
    for (int i = 0; i < per; i++) {
        int idx = base + i;
        int v = (idx < N_NODES) ? counts[idx] : 0;
        loc[i] = s; s += v;
    }
    sums[t] = s;
    __syncthreads();
    for (int off = 1; off < 1024; off <<= 1) {
        int v = (t >= off) ? sums[t - off] : 0;
        __syncthreads();
        sums[t] += v;
        __syncthreads();
    }
    int prefix = (t > 0) ? sums[t - 1] : 0;
    for (int i = 0; i < per; i++) {
        int idx = base + i;
        if (idx < N_NODES) { int r = prefix + loc[i]; rowptr[idx] = r; cursor[idx] = r; }
    }
    if (t == 1023) rowptr[N_NODES] = sums[1023];
}

__global__ void k_scatter(const int* __restrict__ ei, int* cursor, int* csr_src) {
    int e = blockIdx.x * blockDim.x + threadIdx.x;
    if (e < N_EDGES) {
        int s = ei[e], d = ei[N_EDGES + e];
        int pos = atomicAdd(&cursor[d], 1);
        csr_src[pos] = s;
    } else if (e < E2) {
        int n = e - N_EDGES;
        int pos = atomicAdd(&cursor[n], 1);
        csr_src[pos] = n;
    }
}

__global__ void k_bounds(const int* __restrict__ batch, int* gstart, int* gend) {
    int n = blockIdx.x * blockDim.x + threadIdx.x;
    if (n < N_NODES) {
        int b = batch[n];
        atomicMin(&gstart[b], n);
        atomicMax(&gend[b], n + 1);
    }
}

// ---------------- input projection: h = relu(x @ node_W + node_b) ----------------
__global__ void k_input(const float* __restrict__ x, const float* __restrict__ W,
                        const float* __restrict__ b, float* __restrict__ h) {
    int t = blockIdx.x * blockDim.x + threadIdx.x;
    if (t >= N_NODES * HIDDEN) return;
    int n = t >> 7, c = t & 127;
    float s = b[c];
    #pragma unroll
    for (int k = 0; k < 5; k++) s += x[n * 5 + k] * W[k * HIDDEN + c];
    h[t] = fmaxf(s, 0.f);
}

// ---------------- tiled fp32 GEMM: C[M,512] = A[M,128] @ B[128,512] ----------------
#define BM 64
#define BN 64
#define BK 32
__global__ __launch_bounds__(256) void k_gemm(const float* __restrict__ A,
                                              const float* __restrict__ Bw,
                                              float* __restrict__ C) {
    __shared__ float As[BK][BM + 1];
    __shared__ float Bs[BK][BN];
    int tid = threadIdx.x;
    int tx = tid & 15, ty = tid >> 4;
    int mbase = blockIdx.y * BM;
    int nbase = blockIdx.x * BN;
    float acc[4][4] = {};
    for (int k0 = 0; k0 < HIDDEN; k0 += BK) {
        #pragma unroll
        for (int r = 0; r < 2; r++) {
            int idx = tid + r * 256;
            int row = idx >> 3;
            int k4 = (idx & 7) << 2;
            int grow = mbase + row;
            float4 v = make_float4(0.f, 0.f, 0.f, 0.f);
            if (grow < N_NODES) v = *(const float4*)(A + (size_t)grow * HIDDEN + k0 + k4);
            As[k4 + 0][row] = v.x; As[k4 + 1][row] = v.y;
            As[k4 + 2][row] = v.z; As[k4 + 3][row] = v.w;
        }
        #pragma unroll
        for (int r = 0; r < 2; r++) {
            int idx = tid + r * 256;
            int row = idx >> 4;
            int c4 = (idx & 15) << 2;
            *(float4*)(&Bs[row][c4]) = *(const float4*)(Bw + (size_t)(k0 + row) * 512 + nbase + c4);
        }
        __syncthreads();
        #pragma unroll
        for (int k = 0; k < BK; k++) {
            float a0 = As[k][ty * 4 + 0], a1 = As[k][ty * 4 + 1];
            float a2 = As[k][ty * 4 + 2], a3 = As[k][ty * 4 + 3];
            float b0 = Bs[k][tx * 4 + 0], b1 = Bs[k][tx * 4 + 1];
            float b2 = Bs[k][tx * 4 + 2], b3 = Bs[k][tx * 4 + 3];
            acc[0][0] += a0 * b0; acc[0][1] += a0 * b1; acc[0][2] += a0 * b2; acc[0][3] += a0 * b3;
            acc[1][0] += a1 * b0; acc[1][1] += a1 * b1; acc[1][2] += a1 * b2; acc[1][3] += a1 * b3;
            acc[2][0] += a2 * b0; acc[2][1] += a2 * b1; acc[2][2] += a2 * b2; acc[2][3] += a2 * b3;
            acc[3][0] += a3 * b0; acc[3][1] += a3 * b1; acc[3][2] += a3 * b2; acc[3][3] += a3 * b3;
        }
        __syncthreads();
    }
    #pragma unroll
    for (int i = 0; i < 4; i++) {
        int gr = mbase + ty * 4 + i;
        if (gr < N_NODES) {
            float4 v = make_float4(acc[i][0], acc[i][1], acc[i][2], acc[i][3]);
            *(float4*)(C + (size_t)gr * 512 + nbase + tx * 4) = v;
        }
    }
}

// ---------------- attention scores: a_src/a_dst [N, H] ----------------
__global__ void k_att(const float* __restrict__ hp, const float* __restrict__ ws,
                      const float* __restrict__ wd, float* __restrict__ a_src,
                      float* __restrict__ a_dst) {
    int widx = blockIdx.x * 4 + (threadIdx.x >> 6);
    int lane = threadIdx.x & 63;
    if (widx >= N_NODES * NHEAD) return;
    int n = widx >> 2, h = widx & 3;
    const float* row = hp + (size_t)n * 512 + h * 128;
    float v0 = row[lane], v1 = row[lane + 64];
    float s = v0 * ws[h * 128 + lane] + v1 * ws[h * 128 + lane + 64];
    float d = v0 * wd[h * 128 + lane] + v1 * wd[h * 128 + lane + 64];
    #pragma unroll
    for (int o = 32; o > 0; o >>= 1) { s += __shfl_down(s, o); d += __shfl_down(d, o); }
    if (lane == 0) { a_src[widx] = s; a_dst[widx] = d; }
}

// ---------------- fused aggregate + head-mean + LN + relu + residual ----------------
__global__ __launch_bounds__(256) void k_agg(const float* __restrict__ hp,
                                             const int* __restrict__ rowptr,
                                             const int* __restrict__ csr,
                                             const float* __restrict__ a_src,
                                             const float* __restrict__ a_dst,
                                             const float* __restrict__ bias,
                                             const float* __restrict__ lng,
                                             const float* __restrict__ lnb,
                                             float* __restrict__ h) {
    int n = blockIdx.x;
    int tid = threadIdx.x;
    int hh = tid >> 6, lane = tid & 63;
    int off = rowptr[n];
    int deg = rowptr[n + 1] - off;
    float adn = a_dst[n * 4 + hh];
    float m = -INFINITY, denom = 0.f, o0 = 0.f, o1 = 0.f;
    for (int base = 0; base < deg; base += 64) {
        int cnt = min(64, deg - base);
        int s = 0;
        float e = -INFINITY;
        if (lane < cnt) {
            s = csr[off + base + lane];
            float t = a_src[s * 4 + hh] + adn;
            e = t > 0.f ? t : 0.2f * t;
        }
        float cm = e;
        #pragma unroll
        for (int o = 32; o > 0; o >>= 1) cm = fmaxf(cm, __shfl_xor(cm, o));
        float nm = fmaxf(m, cm);
        float scale = (m == -INFINITY) ? 0.f : expf(m - nm);
        o0 *= scale; o1 *= scale; denom *= scale;
        float p = (lane < cnt) ? expf(e - nm) : 0.f;
        float ps = p;
        #pragma unroll
        for (int o = 32; o > 0; o >>= 1) ps += __shfl_xor(ps, o);
        denom += ps;
        for (int i = 0; i < cnt; i++) {
            int si = __shfl(s, i);
            float pi = __shfl(p, i);
            float2 hv = *(const float2*)(hp + (size_t)si * 512 + hh * 128 + lane * 2);
            o0 += pi * hv.x; o1 += pi * hv.y;
        }
        m = nm;
    }
    float inv = 1.f / (denom + 1e-16f);
    o0 *= inv; o1 *= inv;

    __shared__ float hs[4][128];
    __shared__ float red[4];
    hs[hh][lane * 2] = o0;
    hs[hh][lane * 2 + 1] = o1;
    __syncthreads();
    float v = 0.f;
    if (tid < 128) {
        v = 0.25f * (hs[0][tid] + hs[1][tid] + hs[2][tid] + hs[3][tid]) + bias[tid];
        float sv = v, sq = v * v;
        #pragma unroll
        for (int o = 32; o > 0; o >>= 1) { sv += __shfl_down(sv, o); sq += __shfl_down(sq, o); }
        if ((tid & 63) == 0) { red[(tid >> 6) * 2] = sv; red[(tid >> 6) * 2 + 1] = sq; }
    }
    __syncthreads();
    if (tid < 128) {
        float mu = (red[0] + red[2]) * (1.f / 128.f);
        float var = (red[1] + red[3]) * (1.f / 128.f) - mu * mu;
        float rs = rsqrtf(var + LN_EPS);
        float y = (v - mu) * rs * lng[tid] + lnb[tid];
        h[(size_t)n * 128 + tid] = fmaxf(y, 0.f) + h[(size_t)n * 128 + tid];
    }
}

// ---------------- graph mean pool ----------------
__global__ void k_pool(const float* __restrict__ h, const int* __restrict__ gstart,
                       const int* __restrict__ gend, float* __restrict__ out) {
    int b = blockIdx.x, c = threadIdx.x;   // 128 threads
    int s = gstart[b], e = gend[b];
    float acc = 0.f;
    for (int n = s; n < e; n++) acc += h[(size_t)n * 128 + c];
    out[b * 128 + c] = (e > s) ? acc / (float)(e - s) : 0.f;
}

extern "C" void kernel_launch(void* const* d_in, const int* in_sizes, int n_in,
                              void* d_out, int out_size, void* d_ws, size_t ws_size,
                              hipStream_t stream) {
    const float* x      = (const float*)d_in[0];
    const int*   ei     = (const int*)d_in[1];
    const int*   batch  = (const int*)d_in[2];
    const float* node_W = (const float*)d_in[3];
    const float* node_b = (const float*)d_in[4];
    const float* Ws     = (const float*)d_in[5];
    const float* att_s  = (const float*)d_in[6];
    const float* att_d  = (const float*)d_in[7];
    const float* biases = (const float*)d_in[8];
    const float* ln_g   = (const float*)d_in[9];
    const float* ln_b   = (const float*)d_in[10];

    float* out = (float*)d_out;
    float* h = out;                        // h lives in d_out[0 : N*128]
    float* gout = out + (size_t)N_NODES * HIDDEN;

    char* w = (char*)d_ws;
    auto carve = [&](size_t bytes) {
        void* p = (void*)w;
        w += (bytes + 255) & ~(size_t)255;
        return p;
    };
    int* rowptr  = (int*)carve((N_NODES + 1) * sizeof(int));
    int* cursor  = (int*)carve(N_NODES * sizeof(int));
    int* counts  = (int*)carve(N_NODES * sizeof(int));
    int* csr     = (int*)carve(E2 * sizeof(int));
    int* gstart  = (int*)carve(NB * sizeof(int));
    int* gend    = (int*)carve(NB * sizeof(int));
    float* a_src = (float*)carve((size_t)N_NODES * NHEAD * sizeof(float));
    float* a_dst = (float*)carve((size_t)N_NODES * NHEAD * sizeof(float));
    float* hp    = (float*)carve((size_t)N_NODES * 512 * sizeof(float));

    k_init<<<(N_NODES + 255) / 256, 256, 0, stream>>>(counts, gstart, gend);
    k_hist<<<(N_EDGES + 255) / 256, 256, 0, stream>>>(ei, counts);
    k_scan<<<1, 1024, 0, stream>>>(counts, rowptr, cursor);
    k_scatter<<<(E2 + 255) / 256, 256, 0, stream>>>(ei, cursor, csr);
    k_bounds<<<(N_NODES + 255) / 256, 256, 0, stream>>>(batch, gstart, gend);
    k_input<<<(N_NODES * HIDDEN + 255) / 256, 256, 0, stream>>>(x, node_W, node_b, h);

    for (int l = 0; l < 3; l++) {
        k_gemm<<<dim3(512 / BN, (N_NODES + BM - 1) / BM), 256, 0, stream>>>(
            h, Ws + (size_t)l * HIDDEN * 512, hp);
        k_att<<<N_NODES, 256, 0, stream>>>(hp, att_s + l * NHEAD * 128,
                                           att_d + l * NHEAD * 128, a_src, a_dst);
        k_agg<<<N_NODES, 256, 0, stream>>>(hp, rowptr, csr, a_src, a_dst,
                                           biases + l * HIDDEN, ln_g + l * HIDDEN,
                                           ln_b + l * HIDDEN, h);
    }
    k_pool<<<NB, 128, 0, stream>>>(h, gstart, gend, gout);
}

// Round 2
// 450.913 us; speedup vs baseline: 1.1692x; 1.1692x over previous
//
#include <hip/hip_runtime.h>
#include <math.h>

#define N_NODES 10000
#define N_EDGES 160000
#define E2 (N_EDGES + N_NODES)
#define HIDDEN 128
#define NHEAD 4
#define NB 32
#define LN_EPS 1e-5f

// ---------------- CSR build ----------------
__global__ void k_init(int* counts, int* gstart, int* gend, float* gout) {
    int i = blockIdx.x * blockDim.x + threadIdx.x;
    if (i < N_NODES) counts[i] = 1;             // self-loop
    if (i < NB) { gstart[i] = N_NODES; gend[i] = 0; }
    if (i < NB * HIDDEN) gout[i] = 0.f;          // pool accumulator (d_out is poisoned)
}

__global__ void k_hist(const int* __restrict__ ei, int* counts) {
    int e = blockIdx.x * blockDim.x + threadIdx.x;
    if (e < N_EDGES) atomicAdd(&counts[ei[N_EDGES + e]], 1);
}

__global__ void k_scan(const int* __restrict__ counts, int* rowptr, int* cursor) {
    __shared__ int sums[1024];
    int t = threadIdx.x;
    const int per = 10;                          // 1024*10 >= 10000
    int base = t * per;
    int loc[per];
    int s = 0;
    for (int i = 0; i < per; i++) {
        int idx = base + i;
        int v = (idx < N_NODES) ? counts[idx] : 0;
        loc[i] = s; s += v;
    }
    sums[t] = s;
    __syncthreads();
    for (int off = 1; off < 1024; off <<= 1) {
        int v = (t >= off) ? sums[t - off] : 0;
        __syncthreads();
        sums[t] += v;
        __syncthreads();
    }
    int prefix = (t > 0) ? sums[t - 1] : 0;
    for (int i = 0; i < per; i++) {
        int idx = base + i;
        if (idx < N_NODES) { int r = prefix + loc[i]; rowptr[idx] = r; cursor[idx] = r; }
    }
    if (t == 1023) rowptr[N_NODES] = sums[1023];
}

__global__ void k_scatter(const int* __restrict__ ei, int* cursor, int* csr_src) {
    int e = blockIdx.x * blockDim.x + threadIdx.x;
    if (e < N_EDGES) {
        int s = ei[e], d = ei[N_EDGES + e];
        int pos = atomicAdd(&cursor[d], 1);
        csr_src[pos] = s;
    } else if (e < E2) {
        int n = e - N_EDGES;
        int pos = atomicAdd(&cursor[n], 1);
        csr_src[pos] = n;
    }
}

__global__ void k_bounds(const int* __restrict__ batch, int* gstart, int* gend) {
    int n = blockIdx.x * blockDim.x + threadIdx.x;
    if (n < N_NODES) {
        int b = batch[n];
        atomicMin(&gstart[b], n);
        atomicMax(&gend[b], n + 1);
    }
}

// ---------------- input projection: h = relu(x @ node_W + node_b) ----------------
__global__ void k_input(const float* __restrict__ x, const float* __restrict__ W,
                        const float* __restrict__ b, float* __restrict__ h) {
    int t = blockIdx.x * blockDim.x + threadIdx.x;
    if (t >= N_NODES * HIDDEN) return;
    int n = t >> 7, c = t & 127;
    float s = b[c];
    #pragma unroll
    for (int k = 0; k < 5; k++) s += x[n * 5 + k] * W[k * HIDDEN + c];
    h[t] = fmaxf(s, 0.f);
}

// ---------------- tiled fp32 GEMM: C[M,512] = A[M,128] @ B[128,512] ----------------
#define BM 64
#define BN 64
#define BK 32
__global__ __launch_bounds__(256) void k_gemm(const float* __restrict__ A,
                                              const float* __restrict__ Bw,
                                              float* __restrict__ C) {
    __shared__ float As[BK][BM + 1];
    __shared__ float Bs[BK][BN];
    int tid = threadIdx.x;
    int tx = tid & 15, ty = tid >> 4;
    int mbase = blockIdx.y * BM;
    int nbase = blockIdx.x * BN;
    float acc[4][4] = {};
    for (int k0 = 0; k0 < HIDDEN; k0 += BK) {
        #pragma unroll
        for (int r = 0; r < 2; r++) {
            int idx = tid + r * 256;
            int row = idx >> 3;
            int k4 = (idx & 7) << 2;
            int grow = mbase + row;
            float4 v = make_float4(0.f, 0.f, 0.f, 0.f);
            if (grow < N_NODES) v = *(const float4*)(A + (size_t)grow * HIDDEN + k0 + k4);
            As[k4 + 0][row] = v.x; As[k4 + 1][row] = v.y;
            As[k4 + 2][row] = v.z; As[k4 + 3][row] = v.w;
        }
        #pragma unroll
        for (int r = 0; r < 2; r++) {
            int idx = tid + r * 256;
            int row = idx >> 4;
            int c4 = (idx & 15) << 2;
            *(float4*)(&Bs[row][c4]) = *(const float4*)(Bw + (size_t)(k0 + row) * 512 + nbase + c4);
        }
        __syncthreads();
        #pragma unroll
        for (int k = 0; k < BK; k++) {
            float a0 = As[k][ty * 4 + 0], a1 = As[k][ty * 4 + 1];
            float a2 = As[k][ty * 4 + 2], a3 = As[k][ty * 4 + 3];
            float b0 = Bs[k][tx * 4 + 0], b1 = Bs[k][tx * 4 + 1];
            float b2 = Bs[k][tx * 4 + 2], b3 = Bs[k][tx * 4 + 3];
            acc[0][0] += a0 * b0; acc[0][1] += a0 * b1; acc[0][2] += a0 * b2; acc[0][3] += a0 * b3;
            acc[1][0] += a1 * b0; acc[1][1] += a1 * b1; acc[1][2] += a1 * b2; acc[1][3] += a1 * b3;
            acc[2][0] += a2 * b0; acc[2][1] += a2 * b1; acc[2][2] += a2 * b2; acc[2][3] += a2 * b3;
            acc[3][0] += a3 * b0; acc[3][1] += a3 * b1; acc[3][2] += a3 * b2; acc[3][3] += a3 * b3;
        }
        __syncthreads();
    }
    #pragma unroll
    for (int i = 0; i < 4; i++) {
        int gr = mbase + ty * 4 + i;
        if (gr < N_NODES) {
            float4 v = make_float4(acc[i][0], acc[i][1], acc[i][2], acc[i][3]);
            *(float4*)(C + (size_t)gr * 512 + nbase + tx * 4) = v;
        }
    }
}

// ---------------- attention scores: a_src/a_dst [N, H] ----------------
__global__ void k_att(const float* __restrict__ hp, const float* __restrict__ ws,
                      const float* __restrict__ wd, float* __restrict__ a_src,
                      float* __restrict__ a_dst) {
    int widx = blockIdx.x * 4 + (threadIdx.x >> 6);
    int lane = threadIdx.x & 63;
    if (widx >= N_NODES * NHEAD) return;
    int n = widx >> 2, h = widx & 3;
    const float* row = hp + (size_t)n * 512 + h * 128;
    float v0 = row[lane], v1 = row[lane + 64];
    float s = v0 * ws[h * 128 + lane] + v1 * ws[h * 128 + lane + 64];
    float d = v0 * wd[h * 128 + lane] + v1 * wd[h * 128 + lane + 64];
    #pragma unroll
    for (int o = 32; o > 0; o >>= 1) { s += __shfl_down(s, o); d += __shfl_down(d, o); }
    if (lane == 0) { a_src[widx] = s; a_dst[widx] = d; }
}

// ---------------- fused aggregate + head-mean + LN + relu + residual ----------------
__global__ __launch_bounds__(256) void k_agg(const float* __restrict__ hp,
                                             const int* __restrict__ rowptr,
                                             const int* __restrict__ csr,
                                             const float* __restrict__ a_src,
                                             const float* __restrict__ a_dst,
                                             const float* __restrict__ bias,
                                             const float* __restrict__ lng,
                                             const float* __restrict__ lnb,
                                             float* __restrict__ h) {
    int n = blockIdx.x;
    int tid = threadIdx.x;
    int hh = tid >> 6, lane = tid & 63;
    int off = rowptr[n];
    int deg = rowptr[n + 1] - off;
    float adn = a_dst[n * 4 + hh];
    float m = -INFINITY, denom = 0.f, o0 = 0.f, o1 = 0.f;
    for (int base = 0; base < deg; base += 64) {
        int cnt = min(64, deg - base);
        int s = 0;
        float e = -INFINITY;
        if (lane < cnt) {
            s = csr[off + base + lane];
            float t = a_src[s * 4 + hh] + adn;
            e = t > 0.f ? t : 0.2f * t;
        }
        float cm = e;
        #pragma unroll
        for (int o = 32; o > 0; o >>= 1) cm = fmaxf(cm, __shfl_xor(cm, o));
        float nm = fmaxf(m, cm);
        float scale = (m == -INFINITY) ? 0.f : expf(m - nm);
        o0 *= scale; o1 *= scale; denom *= scale;
        float p = (lane < cnt) ? expf(e - nm) : 0.f;
        float ps = p;
        #pragma unroll
        for (int o = 32; o > 0; o >>= 1) ps += __shfl_xor(ps, o);
        denom += ps;
        for (int i = 0; i < cnt; i++) {
            int si = __shfl(s, i);
            float pi = __shfl(p, i);
            float2 hv = *(const float2*)(hp + (size_t)si * 512 + hh * 128 + lane * 2);
            o0 += pi * hv.x; o1 += pi * hv.y;
        }
        m = nm;
    }
    float inv = 1.f / (denom + 1e-16f);
    o0 *= inv; o1 *= inv;

    __shared__ float hs[4][128];
    __shared__ float red[4];
    hs[hh][lane * 2] = o0;
    hs[hh][lane * 2 + 1] = o1;
    __syncthreads();
    float v = 0.f;
    if (tid < 128) {
        v = 0.25f * (hs[0][tid] + hs[1][tid] + hs[2][tid] + hs[3][tid]) + bias[tid];
        float sv = v, sq = v * v;
        #pragma unroll
        for (int o = 32; o > 0; o >>= 1) { sv += __shfl_down(sv, o); sq += __shfl_down(sq, o); }
        if ((tid & 63) == 0) { red[(tid >> 6) * 2] = sv; red[(tid >> 6) * 2 + 1] = sq; }
    }
    __syncthreads();
    if (tid < 128) {
        float mu = (red[0] + red[2]) * (1.f / 128.f);
        float var = (red[1] + red[3]) * (1.f / 128.f) - mu * mu;
        float rs = rsqrtf(var + LN_EPS);
        float y = (v - mu) * rs * lng[tid] + lnb[tid];
        h[(size_t)n * 128 + tid] = fmaxf(y, 0.f) + h[(size_t)n * 128 + tid];
    }
}

// ---------------- graph mean pool (parallel, 3-phase) ----------------
#define POOL_CHUNK 32
__global__ __launch_bounds__(128) void k_pool_sum(const float* __restrict__ h,
                                                  const int* __restrict__ batch,
                                                  float* __restrict__ gout) {
    int n0 = blockIdx.x * POOL_CHUNK;
    int c = threadIdx.x;
    int nend = min(n0 + POOL_CHUNK, N_NODES);
    if (n0 >= N_NODES) return;
    int cur = batch[n0];
    float acc = 0.f;
    for (int n = n0; n < nend; n++) {
        int b = batch[n];                 // sorted: rarely changes within a chunk
        if (b != cur) {
            atomicAdd(&gout[cur * HIDDEN + c], acc);
            acc = 0.f; cur = b;
        }
        acc += h[(size_t)n * HIDDEN + c];
    }
    atomicAdd(&gout[cur * HIDDEN + c], acc);
}

__global__ void k_pool_div(const int* __restrict__ gstart, const int* __restrict__ gend,
                           float* __restrict__ gout) {
    int b = blockIdx.x, c = threadIdx.x;
    int cnt = gend[b] - gstart[b];
    gout[b * HIDDEN + c] *= 1.f / (float)max(cnt, 1);
}

extern "C" void kernel_launch(void* const* d_in, const int* in_sizes, int n_in,
                              void* d_out, int out_size, void* d_ws, size_t ws_size,
                              hipStream_t stream) {
    const float* x      = (const float*)d_in[0];
    const int*   ei     = (const int*)d_in[1];
    const int*   batch  = (const int*)d_in[2];
    const float* node_W = (const float*)d_in[3];
    const float* node_b = (const float*)d_in[4];
    const float* Ws     = (const float*)d_in[5];
    const float* att_s  = (const float*)d_in[6];
    const float* att_d  = (const float*)d_in[7];
    const float* biases = (const float*)d_in[8];
    const float* ln_g   = (const float*)d_in[9];
    const float* ln_b   = (const float*)d_in[10];

    float* out = (float*)d_out;
    float* h = out;                        // h lives in d_out[0 : N*128]
    float* gout = out + (size_t)N_NODES * HIDDEN;

    char* w = (char*)d_ws;
    auto carve = [&](size_t bytes) {
        void* p = (void*)w;
        w += (bytes + 255) & ~(size_t)255;
        return p;
    };
    int* rowptr  = (int*)carve((N_NODES + 1) * sizeof(int));
    int* cursor  = (int*)carve(N_NODES * sizeof(int));
    int* counts  = (int*)carve(N_NODES * sizeof(int));
    int* csr     = (int*)carve(E2 * sizeof(int));
    int* gstart  = (int*)carve(NB * sizeof(int));
    int* gend    = (int*)carve(NB * sizeof(int));
    float* a_src = (float*)carve((size_t)N_NODES * NHEAD * sizeof(float));
    float* a_dst = (float*)carve((size_t)N_NODES * NHEAD * sizeof(float));
    float* hp    = (float*)carve((size_t)N_NODES * 512 * sizeof(float));

    k_init<<<(N_NODES + 255) / 256, 256, 0, stream>>>(counts, gstart, gend, gout);
    k_hist<<<(N_EDGES + 255) / 256, 256, 0, stream>>>(ei, counts);
    k_scan<<<1, 1024, 0, stream>>>(counts, rowptr, cursor);
    k_scatter<<<(E2 + 255) / 256, 256, 0, stream>>>(ei, cursor, csr);
    k_bounds<<<(N_NODES + 255) / 256, 256, 0, stream>>>(batch, gstart, gend);
    k_input<<<(N_NODES * HIDDEN + 255) / 256, 256, 0, stream>>>(x, node_W, node_b, h);

    for (int l = 0; l < 3; l++) {
        k_gemm<<<dim3(512 / BN, (N_NODES + BM - 1) / BM), 256, 0, stream>>>(
            h, Ws + (size_t)l * HIDDEN * 512, hp);
        k_att<<<N_NODES, 256, 0, stream>>>(hp, att_s + l * NHEAD * 128,
                                           att_d + l * NHEAD * 128, a_src, a_dst);
        k_agg<<<N_NODES, 256, 0, stream>>>(hp, rowptr, csr, a_src, a_dst,
                                           biases + l * HIDDEN, ln_g + l * HIDDEN,
                                           ln_b + l * HIDDEN, h);
    }
    k_pool_sum<<<(N_NODES + POOL_CHUNK - 1) / POOL_CHUNK, 128, 0, stream>>>(h, batch, gout);
    k_pool_div<<<NB, HIDDEN, 0, stream>>>(gstart, gend, gout);
}

// Round 3
// 381.849 us; speedup vs baseline: 1.3806x; 1.1809x over previous
//
#include <hip/hip_runtime.h>
#include <math.h>

#define N_NODES 10000
#define N_EDGES 160000
#define E2 (N_EDGES + N_NODES)
#define HIDDEN 128
#define NHEAD 4
#define NB 32
#define LN_EPS 1e-5f

// ---------------- CSR build ----------------
__global__ void k_init(int* counts, int* gstart, int* gend, float* gout) {
    int i = blockIdx.x * blockDim.x + threadIdx.x;
    if (i < N_NODES) counts[i] = 1;             // self-loop
    if (i < NB) { gstart[i] = N_NODES; gend[i] = 0; }
    if (i < NB * HIDDEN) gout[i] = 0.f;          // pool accumulator (d_out is poisoned)
}

__global__ void k_hist(const int* __restrict__ ei, int* counts) {
    int e = blockIdx.x * blockDim.x + threadIdx.x;
    if (e < N_EDGES) atomicAdd(&counts[ei[N_EDGES + e]], 1);
}

__global__ void k_scan(const int* __restrict__ counts, int* rowptr, int* cursor) {
    __shared__ int sums[1024];
    int t = threadIdx.x;
    const int per = 10;                          // 1024*10 >= 10000
    int base = t * per;
    int loc[per];
    int s = 0;
    for (int i = 0; i < per; i++) {
        int idx = base + i;
        int v = (idx < N_NODES) ? counts[idx] : 0;
        loc[i] = s; s += v;
    }
    sums[t] = s;
    __syncthreads();
    for (int off = 1; off < 1024; off <<= 1) {
        int v = (t >= off) ? sums[t - off] : 0;
        __syncthreads();
        sums[t] += v;
        __syncthreads();
    }
    int prefix = (t > 0) ? sums[t - 1] : 0;
    for (int i = 0; i < per; i++) {
        int idx = base + i;
        if (idx < N_NODES) { int r = prefix + loc[i]; rowptr[idx] = r; cursor[idx] = r; }
    }
    if (t == 1023) rowptr[N_NODES] = sums[1023];
}

__global__ void k_scatter(const int* __restrict__ ei, int* cursor, int* csr_src) {
    int e = blockIdx.x * blockDim.x + threadIdx.x;
    if (e < N_EDGES) {
        int s = ei[e], d = ei[N_EDGES + e];
        int pos = atomicAdd(&cursor[d], 1);
        csr_src[pos] = s;
    } else if (e < E2) {
        int n = e - N_EDGES;
        int pos = atomicAdd(&cursor[n], 1);
        csr_src[pos] = n;
    }
}

// batch is sorted: detect graph boundaries locally, no atomics.
__global__ void k_bounds(const int* __restrict__ batch, int* gstart, int* gend) {
    int n = blockIdx.x * blockDim.x + threadIdx.x;
    if (n >= N_NODES) return;
    int b = batch[n];
    if (n == 0 || batch[n - 1] != b) gstart[b] = n;
    if (n == N_NODES - 1 || batch[n + 1] != b) gend[b] = n + 1;
}

// ---------------- input projection: h = relu(x @ node_W + node_b) ----------------
__global__ void k_input(const float* __restrict__ x, const float* __restrict__ W,
                        const float* __restrict__ b, float* __restrict__ h) {
    int t = blockIdx.x * blockDim.x + threadIdx.x;
    if (t >= N_NODES * HIDDEN) return;
    int n = t >> 7, c = t & 127;
    float s = b[c];
    #pragma unroll
    for (int k = 0; k < 5; k++) s += x[n * 5 + k] * W[k * HIDDEN + c];
    h[t] = fmaxf(s, 0.f);
}

// ---------------- tiled fp32 GEMM: C[M,512] = A[M,128] @ B[128,512] ----------------
#define BM 64
#define BN 64
#define BK 32
__global__ __launch_bounds__(256) void k_gemm(const float* __restrict__ A,
                                              const float* __restrict__ Bw,
                                              float* __restrict__ C) {
    __shared__ float As[BK][BM + 1];
    __shared__ float Bs[BK][BN];
    int tid = threadIdx.x;
    int tx = tid & 15, ty = tid >> 4;
    int mbase = blockIdx.y * BM;
    int nbase = blockIdx.x * BN;
    float acc[4][4] = {};
    for (int k0 = 0; k0 < HIDDEN; k0 += BK) {
        #pragma unroll
        for (int r = 0; r < 2; r++) {
            int idx = tid + r * 256;
            int row = idx >> 3;
            int k4 = (idx & 7) << 2;
            int grow = mbase + row;
            float4 v = make_float4(0.f, 0.f, 0.f, 0.f);
            if (grow < N_NODES) v = *(const float4*)(A + (size_t)grow * HIDDEN + k0 + k4);
            As[k4 + 0][row] = v.x; As[k4 + 1][row] = v.y;
            As[k4 + 2][row] = v.z; As[k4 + 3][row] = v.w;
        }
        #pragma unroll
        for (int r = 0; r < 2; r++) {
            int idx = tid + r * 256;
            int row = idx >> 4;
            int c4 = (idx & 15) << 2;
            *(float4*)(&Bs[row][c4]) = *(const float4*)(Bw + (size_t)(k0 + row) * 512 + nbase + c4);
        }
        __syncthreads();
        #pragma unroll
        for (int k = 0; k < BK; k++) {
            float a0 = As[k][ty * 4 + 0], a1 = As[k][ty * 4 + 1];
            float a2 = As[k][ty * 4 + 2], a3 = As[k][ty * 4 + 3];
            float b0 = Bs[k][tx * 4 + 0], b1 = Bs[k][tx * 4 + 1];
            float b2 = Bs[k][tx * 4 + 2], b3 = Bs[k][tx * 4 + 3];
            acc[0][0] += a0 * b0; acc[0][1] += a0 * b1; acc[0][2] += a0 * b2; acc[0][3] += a0 * b3;
            acc[1][0] += a1 * b0; acc[1][1] += a1 * b1; acc[1][2] += a1 * b2; acc[1][3] += a1 * b3;
            acc[2][0] += a2 * b0; acc[2][1] += a2 * b1; acc[2][2] += a2 * b2; acc[2][3] += a2 * b3;
            acc[3][0] += a3 * b0; acc[3][1] += a3 * b1; acc[3][2] += a3 * b2; acc[3][3] += a3 * b3;
        }
        __syncthreads();
    }
    #pragma unroll
    for (int i = 0; i < 4; i++) {
        int gr = mbase + ty * 4 + i;
        if (gr < N_NODES) {
            float4 v = make_float4(acc[i][0], acc[i][1], acc[i][2], acc[i][3]);
            *(float4*)(C + (size_t)gr * 512 + nbase + tx * 4) = v;
        }
    }
}

// ---------------- attention scores: a_src/a_dst [N, H] ----------------
__global__ void k_att(const float* __restrict__ hp, const float* __restrict__ ws,
                      const float* __restrict__ wd, float* __restrict__ a_src,
                      float* __restrict__ a_dst) {
    int widx = blockIdx.x * 4 + (threadIdx.x >> 6);
    int lane = threadIdx.x & 63;
    if (widx >= N_NODES * NHEAD) return;
    int n = widx >> 2, h = widx & 3;
    const float* row = hp + (size_t)n * 512 + h * 128;
    float v0 = row[lane], v1 = row[lane + 64];
    float s = v0 * ws[h * 128 + lane] + v1 * ws[h * 128 + lane + 64];
    float d = v0 * wd[h * 128 + lane] + v1 * wd[h * 128 + lane + 64];
    #pragma unroll
    for (int o = 32; o > 0; o >>= 1) { s += __shfl_down(s, o); d += __shfl_down(d, o); }
    if (lane == 0) { a_src[widx] = s; a_dst[widx] = d; }
}

// ---------------- fused aggregate + head-mean + LN + relu + residual ----------------
__global__ __launch_bounds__(256) void k_agg(const float* __restrict__ hp,
                                             const int* __restrict__ rowptr,
                                             const int* __restrict__ csr,
                                             const float* __restrict__ a_src,
                                             const float* __restrict__ a_dst,
                                             const float* __restrict__ bias,
                                             const float* __restrict__ lng,
                                             const float* __restrict__ lnb,
                                             float* __restrict__ h) {
    int n = blockIdx.x;
    int tid = threadIdx.x;
    int hh = tid >> 6, lane = tid & 63;
    int off = rowptr[n];
    int deg = rowptr[n + 1] - off;
    float adn = a_dst[n * 4 + hh];
    float m = -INFINITY, denom = 0.f, o0 = 0.f, o1 = 0.f;
    for (int base = 0; base < deg; base += 64) {
        int cnt = min(64, deg - base);
        int s = 0;
        float e = -INFINITY;
        if (lane < cnt) {
            s = csr[off + base + lane];
            float t = a_src[s * 4 + hh] + adn;
            e = t > 0.f ? t : 0.2f * t;
        }
        float cm = e;
        #pragma unroll
        for (int o = 32; o > 0; o >>= 1) cm = fmaxf(cm, __shfl_xor(cm, o));
        float nm = fmaxf(m, cm);
        float scale = (m == -INFINITY) ? 0.f : expf(m - nm);
        o0 *= scale; o1 *= scale; denom *= scale;
        float p = (lane < cnt) ? expf(e - nm) : 0.f;
        float ps = p;
        #pragma unroll
        for (int o = 32; o > 0; o >>= 1) ps += __shfl_xor(ps, o);
        denom += ps;
        for (int i = 0; i < cnt; i++) {
            int si = __shfl(s, i);
            float pi = __shfl(p, i);
            float2 hv = *(const float2*)(hp + (size_t)si * 512 + hh * 128 + lane * 2);
            o0 += pi * hv.x; o1 += pi * hv.y;
        }
        m = nm;
    }
    float inv = 1.f / (denom + 1e-16f);
    o0 *= inv; o1 *= inv;

    __shared__ float hs[4][128];
    __shared__ float red[4];
    hs[hh][lane * 2] = o0;
    hs[hh][lane * 2 + 1] = o1;
    __syncthreads();
    float v = 0.f;
    if (tid < 128) {
        v = 0.25f * (hs[0][tid] + hs[1][tid] + hs[2][tid] + hs[3][tid]) + bias[tid];
        float sv = v, sq = v * v;
        #pragma unroll
        for (int o = 32; o > 0; o >>= 1) { sv += __shfl_down(sv, o); sq += __shfl_down(sq, o); }
        if ((tid & 63) == 0) { red[(tid >> 6) * 2] = sv; red[(tid >> 6) * 2 + 1] = sq; }
    }
    __syncthreads();
    if (tid < 128) {
        float mu = (red[0] + red[2]) * (1.f / 128.f);
        float var = (red[1] + red[3]) * (1.f / 128.f) - mu * mu;
        float rs = rsqrtf(var + LN_EPS);
        float y = (v - mu) * rs * lng[tid] + lnb[tid];
        h[(size_t)n * 128 + tid] = fmaxf(y, 0.f) + h[(size_t)n * 128 + tid];
    }
}

// ---------------- graph mean pool (parallel, 3-phase) ----------------
#define POOL_CHUNK 32
__global__ __launch_bounds__(128) void k_pool_sum(const float* __restrict__ h,
                                                  const int* __restrict__ batch,
                                                  float* __restrict__ gout) {
    int n0 = blockIdx.x * POOL_CHUNK;
    int c = threadIdx.x;
    int nend = min(n0 + POOL_CHUNK, N_NODES);
    if (n0 >= N_NODES) return;
    int cur = batch[n0];
    float acc = 0.f;
    for (int n = n0; n < nend; n++) {
        int b = batch[n];                 // sorted: rarely changes within a chunk
        if (b != cur) {
            atomicAdd(&gout[cur * HIDDEN + c], acc);
            acc = 0.f; cur = b;
        }
        acc += h[(size_t)n * HIDDEN + c];
    }
    atomicAdd(&gout[cur * HIDDEN + c], acc);
}

__global__ void k_pool_div(const int* __restrict__ gstart, const int* __restrict__ gend,
                           float* __restrict__ gout) {
    int b = blockIdx.x, c = threadIdx.x;
    int cnt = gend[b] - gstart[b];
    gout[b * HIDDEN + c] *= 1.f / (float)max(cnt, 1);
}

extern "C" void kernel_launch(void* const* d_in, const int* in_sizes, int n_in,
                              void* d_out, int out_size, void* d_ws, size_t ws_size,
                              hipStream_t stream) {
    const float* x      = (const float*)d_in[0];
    const int*   ei     = (const int*)d_in[1];
    const int*   batch  = (const int*)d_in[2];
    const float* node_W = (const float*)d_in[3];
    const float* node_b = (const float*)d_in[4];
    const float* Ws     = (const float*)d_in[5];
    const float* att_s  = (const float*)d_in[6];
    const float* att_d  = (const float*)d_in[7];
    const float* biases = (const float*)d_in[8];
    const float* ln_g   = (const float*)d_in[9];
    const float* ln_b   = (const float*)d_in[10];

    float* out = (float*)d_out;
    float* h = out;                        // h lives in d_out[0 : N*128]
    float* gout = out + (size_t)N_NODES * HIDDEN;

    char* w = (char*)d_ws;
    auto carve = [&](size_t bytes) {
        void* p = (void*)w;
        w += (bytes + 255) & ~(size_t)255;
        return p;
    };
    int* rowptr  = (int*)carve((N_NODES + 1) * sizeof(int));
    int* cursor  = (int*)carve(N_NODES * sizeof(int));
    int* counts  = (int*)carve(N_NODES * sizeof(int));
    int* csr     = (int*)carve(E2 * sizeof(int));
    int* gstart  = (int*)carve(NB * sizeof(int));
    int* gend    = (int*)carve(NB * sizeof(int));
    float* a_src = (float*)carve((size_t)N_NODES * NHEAD * sizeof(float));
    float* a_dst = (float*)carve((size_t)N_NODES * NHEAD * sizeof(float));
    float* hp    = (float*)carve((size_t)N_NODES * 512 * sizeof(float));

    k_init<<<(N_NODES + 255) / 256, 256, 0, stream>>>(counts, gstart, gend, gout);
    k_hist<<<(N_EDGES + 255) / 256, 256, 0, stream>>>(ei, counts);
    k_scan<<<1, 1024, 0, stream>>>(counts, rowptr, cursor);
    k_scatter<<<(E2 + 255) / 256, 256, 0, stream>>>(ei, cursor, csr);
    k_bounds<<<(N_NODES + 255) / 256, 256, 0, stream>>>(batch, gstart, gend);
    k_input<<<(N_NODES * HIDDEN + 255) / 256, 256, 0, stream>>>(x, node_W, node_b, h);

    for (int l = 0; l < 3; l++) {
        k_gemm<<<dim3(512 / BN, (N_NODES + BM - 1) / BM), 256, 0, stream>>>(
            h, Ws + (size_t)l * HIDDEN * 512, hp);
        k_att<<<N_NODES, 256, 0, stream>>>(hp, att_s + l * NHEAD * 128,
                                           att_d + l * NHEAD * 128, a_src, a_dst);
        k_agg<<<N_NODES, 256, 0, stream>>>(hp, rowptr, csr, a_src, a_dst,
                                           biases + l * HIDDEN, ln_g + l * HIDDEN,
                                           ln_b + l * HIDDEN, h);
    }
    k_pool_sum<<<(N_NODES + POOL_CHUNK - 1) / POOL_CHUNK, 128, 0, stream>>>(h, batch, gout);
    k_pool_div<<<NB, HIDDEN, 0, stream>>>(gstart, gend, gout);
}

// Round 4
// 364.196 us; speedup vs baseline: 1.4475x; 1.0485x over previous
//
#include <hip/hip_runtime.h>
#include <math.h>

#define N_NODES 10000
#define N_EDGES 160000
#define E2 (N_EDGES + N_NODES)
#define HIDDEN 128
#define NHEAD 4
#define NB 32
#define LN_EPS 1e-5f

__device__ __forceinline__ unsigned short f2bf(float f) {
    unsigned int u = __float_as_uint(f);
    u += 0x7fffu + ((u >> 16) & 1u);       // RNE
    return (unsigned short)(u >> 16);
}
__device__ __forceinline__ float bf2f_lo(unsigned int u) { return __uint_as_float(u << 16); }
__device__ __forceinline__ float bf2f_hi(unsigned int u) { return __uint_as_float(u & 0xffff0000u); }

// ---------------- CSR build ----------------
__global__ void k_init(int* counts, int* gstart, int* gend, float* gout) {
    int i = blockIdx.x * blockDim.x + threadIdx.x;
    if (i < N_NODES) counts[i] = 1;             // self-loop
    if (i < NB) { gstart[i] = N_NODES; gend[i] = 0; }
    if (i < NB * HIDDEN) gout[i] = 0.f;          // pool accumulator (d_out is poisoned)
}

__global__ void k_hist(const int* __restrict__ ei, int* counts) {
    int e = blockIdx.x * blockDim.x + threadIdx.x;
    if (e < N_EDGES) atomicAdd(&counts[ei[N_EDGES + e]], 1);
}

__global__ void k_scan(const int* __restrict__ counts, int* rowptr, int* cursor) {
    __shared__ int sums[1024];
    int t = threadIdx.x;
    const int per = 10;                          // 1024*10 >= 10000
    int base = t * per;
    int loc[per];
    int s = 0;
    for (int i = 0; i < per; i++) {
        int idx = base + i;
        int v = (idx < N_NODES) ? counts[idx] : 0;
        loc[i] = s; s += v;
    }
    sums[t] = s;
    __syncthreads();
    for (int off = 1; off < 1024; off <<= 1) {
        int v = (t >= off) ? sums[t - off] : 0;
        __syncthreads();
        sums[t] += v;
        __syncthreads();
    }
    int prefix = (t > 0) ? sums[t - 1] : 0;
    for (int i = 0; i < per; i++) {
        int idx = base + i;
        if (idx < N_NODES) { int r = prefix + loc[i]; rowptr[idx] = r; cursor[idx] = r; }
    }
    if (t == 1023) rowptr[N_NODES] = sums[1023];
}

__global__ void k_scatter(const int* __restrict__ ei, int* cursor, int* csr_src) {
    int e = blockIdx.x * blockDim.x + threadIdx.x;
    if (e < N_EDGES) {
        int s = ei[e], d = ei[N_EDGES + e];
        int pos = atomicAdd(&cursor[d], 1);
        csr_src[pos] = s;
    } else if (e < E2) {
        int n = e - N_EDGES;
        int pos = atomicAdd(&cursor[n], 1);
        csr_src[pos] = n;
    }
}

// batch is sorted: detect graph boundaries locally, no atomics.
__global__ void k_bounds(const int* __restrict__ batch, int* gstart, int* gend) {
    int n = blockIdx.x * blockDim.x + threadIdx.x;
    if (n >= N_NODES) return;
    int b = batch[n];
    if (n == 0 || batch[n - 1] != b) gstart[b] = n;
    if (n == N_NODES - 1 || batch[n + 1] != b) gend[b] = n + 1;
}

// ---------------- input projection: h = relu(x @ node_W + node_b) ----------------
__global__ void k_input(const float* __restrict__ x, const float* __restrict__ W,
                        const float* __restrict__ b, float* __restrict__ h) {
    int t = blockIdx.x * blockDim.x + threadIdx.x;
    if (t >= N_NODES * HIDDEN) return;
    int n = t >> 7, c = t & 127;
    float s = b[c];
    #pragma unroll
    for (int k = 0; k < 5; k++) s += x[n * 5 + k] * W[k * HIDDEN + c];
    h[t] = fmaxf(s, 0.f);
}

// ---------------- tiled fp32 GEMM: hp[M,512] = A[M,128] @ B[128,512], bf16 out ----
#define BM 64
#define BN 64
#define BK 32
__global__ __launch_bounds__(256) void k_gemm(const float* __restrict__ A,
                                              const float* __restrict__ Bw,
                                              unsigned short* __restrict__ Cb) {
    __shared__ float As[BK][BM + 1];
    __shared__ float Bs[BK][BN];
    int tid = threadIdx.x;
    int tx = tid & 15, ty = tid >> 4;
    int mbase = blockIdx.y * BM;
    int nbase = blockIdx.x * BN;
    float acc[4][4] = {};
    for (int k0 = 0; k0 < HIDDEN; k0 += BK) {
        #pragma unroll
        for (int r = 0; r < 2; r++) {
            int idx = tid + r * 256;
            int row = idx >> 3;
            int k4 = (idx & 7) << 2;
            int grow = mbase + row;
            float4 v = make_float4(0.f, 0.f, 0.f, 0.f);
            if (grow < N_NODES) v = *(const float4*)(A + (size_t)grow * HIDDEN + k0 + k4);
            As[k4 + 0][row] = v.x; As[k4 + 1][row] = v.y;
            As[k4 + 2][row] = v.z; As[k4 + 3][row] = v.w;
        }
        #pragma unroll
        for (int r = 0; r < 2; r++) {
            int idx = tid + r * 256;
            int row = idx >> 4;
            int c4 = (idx & 15) << 2;
            *(float4*)(&Bs[row][c4]) = *(const float4*)(Bw + (size_t)(k0 + row) * 512 + nbase + c4);
        }
        __syncthreads();
        #pragma unroll
        for (int k = 0; k < BK; k++) {
            float a0 = As[k][ty * 4 + 0], a1 = As[k][ty * 4 + 1];
            float a2 = As[k][ty * 4 + 2], a3 = As[k][ty * 4 + 3];
            float b0 = Bs[k][tx * 4 + 0], b1 = Bs[k][tx * 4 + 1];
            float b2 = Bs[k][tx * 4 + 2], b3 = Bs[k][tx * 4 + 3];
            acc[0][0] += a0 * b0; acc[0][1] += a0 * b1; acc[0][2] += a0 * b2; acc[0][3] += a0 * b3;
            acc[1][0] += a1 * b0; acc[1][1] += a1 * b1; acc[1][2] += a1 * b2; acc[1][3] += a1 * b3;
            acc[2][0] += a2 * b0; acc[2][1] += a2 * b1; acc[2][2] += a2 * b2; acc[2][3] += a2 * b3;
            acc[3][0] += a3 * b0; acc[3][1] += a3 * b1; acc[3][2] += a3 * b2; acc[3][3] += a3 * b3;
        }
        __syncthreads();
    }
    #pragma unroll
    for (int i = 0; i < 4; i++) {
        int gr = mbase + ty * 4 + i;
        if (gr < N_NODES) {
            ushort4 v;
            v.x = f2bf(acc[i][0]); v.y = f2bf(acc[i][1]);
            v.z = f2bf(acc[i][2]); v.w = f2bf(acc[i][3]);
            *(ushort4*)(Cb + (size_t)gr * 512 + nbase + tx * 4) = v;
        }
    }
}

// ---------------- attention scores: a_src/a_dst [N, H] (bf16 hp) ----------------
__global__ void k_att(const unsigned int* __restrict__ hb32,   // bf16 pairs
                      const float* __restrict__ ws,
                      const float* __restrict__ wd, float* __restrict__ a_src,
                      float* __restrict__ a_dst) {
    int widx = blockIdx.x * 4 + (threadIdx.x >> 6);
    int lane = threadIdx.x & 63;
    if (widx >= N_NODES * NHEAD) return;
    int n = widx >> 2, h = widx & 3;
    // row = 512 bf16 per node = 256 dwords; head h occupies dwords [h*64, h*64+64)
    unsigned int u = hb32[(size_t)n * 256 + h * 64 + lane];
    float v0 = bf2f_lo(u), v1 = bf2f_hi(u);
    int c = 2 * lane;
    float s = v0 * ws[h * 128 + c] + v1 * ws[h * 128 + c + 1];
    float d = v0 * wd[h * 128 + c] + v1 * wd[h * 128 + c + 1];
    #pragma unroll
    for (int o = 32; o > 0; o >>= 1) { s += __shfl_down(s, o); d += __shfl_down(d, o); }
    if (lane == 0) { a_src[widx] = s; a_dst[widx] = d; }
}

// ---------------- fused aggregate + head-mean + LN + relu + residual ----------------
__global__ __launch_bounds__(256) void k_agg(const unsigned int* __restrict__ hb32,
                                             const int* __restrict__ rowptr,
                                             const int* __restrict__ csr,
                                             const float* __restrict__ a_src,
                                             const float* __restrict__ a_dst,
                                             const float* __restrict__ bias,
                                             const float* __restrict__ lng,
                                             const float* __restrict__ lnb,
                                             float* __restrict__ h) {
    int n = blockIdx.x;
    int tid = threadIdx.x;
    int hh = tid >> 6, lane = tid & 63;
    int off = rowptr[n];
    int deg = rowptr[n + 1] - off;
    float adn = a_dst[n * 4 + hh];
    float m = -INFINITY, denom = 0.f, o0 = 0.f, o1 = 0.f;
    for (int base = 0; base < deg; base += 64) {
        int cnt = min(64, deg - base);
        int s = 0;
        float e = -INFINITY;
        if (lane < cnt) {
            s = csr[off + base + lane];
            float t = a_src[s * 4 + hh] + adn;
            e = t > 0.f ? t : 0.2f * t;
        }
        float cm = e;
        #pragma unroll
        for (int o = 32; o > 0; o >>= 1) cm = fmaxf(cm, __shfl_xor(cm, o));
        float nm = fmaxf(m, cm);
        float scale = (m == -INFINITY) ? 0.f : expf(m - nm);
        o0 *= scale; o1 *= scale; denom *= scale;
        float p = (lane < cnt) ? expf(e - nm) : 0.f;
        float ps = p;
        #pragma unroll
        for (int o = 32; o > 0; o >>= 1) ps += __shfl_xor(ps, o);
        denom += ps;
        for (int i = 0; i < cnt; i++) {
            int si = __shfl(s, i);
            float pi = __shfl(p, i);
            // head hh channels [2*lane, 2*lane+1] -> dword index si*256 + hh*64 + lane
            unsigned int u = hb32[(size_t)si * 256 + hh * 64 + lane];
            o0 += pi * bf2f_lo(u); o1 += pi * bf2f_hi(u);
        }
        m = nm;
    }
    float inv = 1.f / (denom + 1e-16f);
    o0 *= inv; o1 *= inv;

    __shared__ float hs[4][128];
    __shared__ float red[4];
    hs[hh][lane * 2] = o0;
    hs[hh][lane * 2 + 1] = o1;
    __syncthreads();
    float v = 0.f;
    if (tid < 128) {
        v = 0.25f * (hs[0][tid] + hs[1][tid] + hs[2][tid] + hs[3][tid]) + bias[tid];
        float sv = v, sq = v * v;
        #pragma unroll
        for (int o = 32; o > 0; o >>= 1) { sv += __shfl_down(sv, o); sq += __shfl_down(sq, o); }
        if ((tid & 63) == 0) { red[(tid >> 6) * 2] = sv; red[(tid >> 6) * 2 + 1] = sq; }
    }
    __syncthreads();
    if (tid < 128) {
        float mu = (red[0] + red[2]) * (1.f / 128.f);
        float var = (red[1] + red[3]) * (1.f / 128.f) - mu * mu;
        float rs = rsqrtf(var + LN_EPS);
        float y = (v - mu) * rs * lng[tid] + lnb[tid];
        h[(size_t)n * 128 + tid] = fmaxf(y, 0.f) + h[(size_t)n * 128 + tid];
    }
}

// ---------------- graph mean pool (parallel, 3-phase) ----------------
#define POOL_CHUNK 32
__global__ __launch_bounds__(128) void k_pool_sum(const float* __restrict__ h,
                                                  const int* __restrict__ batch,
                                                  float* __restrict__ gout) {
    int n0 = blockIdx.x * POOL_CHUNK;
    int c = threadIdx.x;
    int nend = min(n0 + POOL_CHUNK, N_NODES);
    if (n0 >= N_NODES) return;
    int cur = batch[n0];
    float acc = 0.f;
    for (int n = n0; n < nend; n++) {
        int b = batch[n];                 // sorted: rarely changes within a chunk
        if (b != cur) {
            atomicAdd(&gout[cur * HIDDEN + c], acc);
            acc = 0.f; cur = b;
        }
        acc += h[(size_t)n * HIDDEN + c];
    }
    atomicAdd(&gout[cur * HIDDEN + c], acc);
}

__global__ void k_pool_div(const int* __restrict__ gstart, const int* __restrict__ gend,
                           float* __restrict__ gout) {
    int b = blockIdx.x, c = threadIdx.x;
    int cnt = gend[b] - gstart[b];
    gout[b * HIDDEN + c] *= 1.f / (float)max(cnt, 1);
}

extern "C" void kernel_launch(void* const* d_in, const int* in_sizes, int n_in,
                              void* d_out, int out_size, void* d_ws, size_t ws_size,
                              hipStream_t stream) {
    const float* x      = (const float*)d_in[0];
    const int*   ei     = (const int*)d_in[1];
    const int*   batch  = (const int*)d_in[2];
    const float* node_W = (const float*)d_in[3];
    const float* node_b = (const float*)d_in[4];
    const float* Ws     = (const float*)d_in[5];
    const float* att_s  = (const float*)d_in[6];
    const float* att_d  = (const float*)d_in[7];
    const float* biases = (const float*)d_in[8];
    const float* ln_g   = (const float*)d_in[9];
    const float* ln_b   = (const float*)d_in[10];

    float* out = (float*)d_out;
    float* h = out;                        // h lives in d_out[0 : N*128]
    float* gout = out + (size_t)N_NODES * HIDDEN;

    char* w = (char*)d_ws;
    auto carve = [&](size_t bytes) {
        void* p = (void*)w;
        w += (bytes + 255) & ~(size_t)255;
        return p;
    };
    int* rowptr  = (int*)carve((N_NODES + 1) * sizeof(int));
    int* cursor  = (int*)carve(N_NODES * sizeof(int));
    int* counts  = (int*)carve(N_NODES * sizeof(int));
    int* csr     = (int*)carve(E2 * sizeof(int));
    int* gstart  = (int*)carve(NB * sizeof(int));
    int* gend    = (int*)carve(NB * sizeof(int));
    float* a_src = (float*)carve((size_t)N_NODES * NHEAD * sizeof(float));
    float* a_dst = (float*)carve((size_t)N_NODES * NHEAD * sizeof(float));
    unsigned short* hb = (unsigned short*)carve((size_t)N_NODES * 512 * sizeof(unsigned short));

    k_init<<<(N_NODES + 255) / 256, 256, 0, stream>>>(counts, gstart, gend, gout);
    k_hist<<<(N_EDGES + 255) / 256, 256, 0, stream>>>(ei, counts);
    k_scan<<<1, 1024, 0, stream>>>(counts, rowptr, cursor);
    k_scatter<<<(E2 + 255) / 256, 256, 0, stream>>>(ei, cursor, csr);
    k_bounds<<<(N_NODES + 255) / 256, 256, 0, stream>>>(batch, gstart, gend);
    k_input<<<(N_NODES * HIDDEN + 255) / 256, 256, 0, stream>>>(x, node_W, node_b, h);

    for (int l = 0; l < 3; l++) {
        k_gemm<<<dim3(512 / BN, (N_NODES + BM - 1) / BM), 256, 0, stream>>>(
            h, Ws + (size_t)l * HIDDEN * 512, hb);
        k_att<<<N_NODES, 256, 0, stream>>>((const unsigned int*)hb,
                                           att_s + l * NHEAD * 128,
                                           att_d + l * NHEAD * 128, a_src, a_dst);
        k_agg<<<N_NODES, 256, 0, stream>>>((const unsigned int*)hb, rowptr, csr,
                                           a_src, a_dst,
                                           biases + l * HIDDEN, ln_g + l * HIDDEN,
                                           ln_b + l * HIDDEN, h);
    }
    k_pool_sum<<<(N_NODES + POOL_CHUNK - 1) / POOL_CHUNK, 128, 0, stream>>>(h, batch, gout);
    k_pool_div<<<NB, HIDDEN, 0, stream>>>(gstart, gend, gout);
}

// Round 5
// 303.205 us; speedup vs baseline: 1.7387x; 1.2012x over previous
//
#include <hip/hip_runtime.h>
#include <math.h>

#define N_NODES 10000
#define N_EDGES 160000
#define E2 (N_EDGES + N_NODES)
#define HIDDEN 128
#define NHEAD 4
#define NB 32
#define LN_EPS 1e-5f

__device__ __forceinline__ unsigned short f2bf(float f) {
    unsigned int u = __float_as_uint(f);
    u += 0x7fffu + ((u >> 16) & 1u);       // RNE
    return (unsigned short)(u >> 16);
}
__device__ __forceinline__ float bf2f_lo(unsigned int u) { return __uint_as_float(u << 16); }
__device__ __forceinline__ float bf2f_hi(unsigned int u) { return __uint_as_float(u & 0xffff0000u); }

// ---------------- CSR build ----------------
__global__ void k_init(int* counts, int* gstart, int* gend, float* gout) {
    int i = blockIdx.x * blockDim.x + threadIdx.x;
    if (i < N_NODES) counts[i] = 1;             // self-loop
    if (i < NB) { gstart[i] = N_NODES; gend[i] = 0; }
    if (i < NB * HIDDEN) gout[i] = 0.f;          // pool accumulator (d_out is poisoned)
}

__global__ void k_hist(const int* __restrict__ ei, int* counts) {
    int e = blockIdx.x * blockDim.x + threadIdx.x;
    if (e < N_EDGES) atomicAdd(&counts[ei[N_EDGES + e]], 1);
}

__global__ void k_scan(const int* __restrict__ counts, int* rowptr, int* cursor) {
    __shared__ int sums[1024];
    int t = threadIdx.x;
    const int per = 10;                          // 1024*10 >= 10000
    int base = t * per;
    int loc[per];
    int s = 0;
    for (int i = 0; i < per; i++) {
        int idx = base + i;
        int v = (idx < N_NODES) ? counts[idx] : 0;
        loc[i] = s; s += v;
    }
    sums[t] = s;
    __syncthreads();
    for (int off = 1; off < 1024; off <<= 1) {
        int v = (t >= off) ? sums[t - off] : 0;
        __syncthreads();
        sums[t] += v;
        __syncthreads();
    }
    int prefix = (t > 0) ? sums[t - 1] : 0;
    for (int i = 0; i < per; i++) {
        int idx = base + i;
        if (idx < N_NODES) { int r = prefix + loc[i]; rowptr[idx] = r; cursor[idx] = r; }
    }
    if (t == 1023) rowptr[N_NODES] = sums[1023];
}

__global__ void k_scatter(const int* __restrict__ ei, int* cursor, int* csr_src) {
    int e = blockIdx.x * blockDim.x + threadIdx.x;
    if (e < N_EDGES) {
        int s = ei[e], d = ei[N_EDGES + e];
        int pos = atomicAdd(&cursor[d], 1);
        csr_src[pos] = s;
    } else if (e < E2) {
        int n = e - N_EDGES;
        int pos = atomicAdd(&cursor[n], 1);
        csr_src[pos] = n;
    }
}

// batch is sorted: detect graph boundaries locally, no atomics.
__global__ void k_bounds(const int* __restrict__ batch, int* gstart, int* gend) {
    int n = blockIdx.x * blockDim.x + threadIdx.x;
    if (n >= N_NODES) return;
    int b = batch[n];
    if (n == 0 || batch[n - 1] != b) gstart[b] = n;
    if (n == N_NODES - 1 || batch[n + 1] != b) gend[b] = n + 1;
}

// ---------------- input projection: h = relu(x @ node_W + node_b) ----------------
__global__ void k_input(const float* __restrict__ x, const float* __restrict__ W,
                        const float* __restrict__ b, float* __restrict__ h) {
    int t = blockIdx.x * blockDim.x + threadIdx.x;
    if (t >= N_NODES * HIDDEN) return;
    int n = t >> 7, c = t & 127;
    float s = b[c];
    #pragma unroll
    for (int k = 0; k < 5; k++) s += x[n * 5 + k] * W[k * HIDDEN + c];
    h[t] = fmaxf(s, 0.f);
}

// ---------------- tiled fp32 GEMM: hp[M,512] = A[M,128] @ B[128,512], bf16 out ----
#define BM 64
#define BN 64
#define BK 32
__global__ __launch_bounds__(256) void k_gemm(const float* __restrict__ A,
                                              const float* __restrict__ Bw,
                                              unsigned short* __restrict__ Cb) {
    __shared__ float As[BK][BM + 1];
    __shared__ float Bs[BK][BN];
    int tid = threadIdx.x;
    int tx = tid & 15, ty = tid >> 4;
    int mbase = blockIdx.y * BM;
    int nbase = blockIdx.x * BN;
    float acc[4][4] = {};
    for (int k0 = 0; k0 < HIDDEN; k0 += BK) {
        #pragma unroll
        for (int r = 0; r < 2; r++) {
            int idx = tid + r * 256;
            int row = idx >> 3;
            int k4 = (idx & 7) << 2;
            int grow = mbase + row;
            float4 v = make_float4(0.f, 0.f, 0.f, 0.f);
            if (grow < N_NODES) v = *(const float4*)(A + (size_t)grow * HIDDEN + k0 + k4);
            As[k4 + 0][row] = v.x; As[k4 + 1][row] = v.y;
            As[k4 + 2][row] = v.z; As[k4 + 3][row] = v.w;
        }
        #pragma unroll
        for (int r = 0; r < 2; r++) {
            int idx = tid + r * 256;
            int row = idx >> 4;
            int c4 = (idx & 15) << 2;
            *(float4*)(&Bs[row][c4]) = *(const float4*)(Bw + (size_t)(k0 + row) * 512 + nbase + c4);
        }
        __syncthreads();
        #pragma unroll
        for (int k = 0; k < BK; k++) {
            float a0 = As[k][ty * 4 + 0], a1 = As[k][ty * 4 + 1];
            float a2 = As[k][ty * 4 + 2], a3 = As[k][ty * 4 + 3];
            float b0 = Bs[k][tx * 4 + 0], b1 = Bs[k][tx * 4 + 1];
            float b2 = Bs[k][tx * 4 + 2], b3 = Bs[k][tx * 4 + 3];
            acc[0][0] += a0 * b0; acc[0][1] += a0 * b1; acc[0][2] += a0 * b2; acc[0][3] += a0 * b3;
            acc[1][0] += a1 * b0; acc[1][1] += a1 * b1; acc[1][2] += a1 * b2; acc[1][3] += a1 * b3;
            acc[2][0] += a2 * b0; acc[2][1] += a2 * b1; acc[2][2] += a2 * b2; acc[2][3] += a2 * b3;
            acc[3][0] += a3 * b0; acc[3][1] += a3 * b1; acc[3][2] += a3 * b2; acc[3][3] += a3 * b3;
        }
        __syncthreads();
    }
    #pragma unroll
    for (int i = 0; i < 4; i++) {
        int gr = mbase + ty * 4 + i;
        if (gr < N_NODES) {
            ushort4 v;
            v.x = f2bf(acc[i][0]); v.y = f2bf(acc[i][1]);
            v.z = f2bf(acc[i][2]); v.w = f2bf(acc[i][3]);
            *(ushort4*)(Cb + (size_t)gr * 512 + nbase + tx * 4) = v;
        }
    }
}

// ---------------- attention scores: a_src/a_dst [N, H] (bf16 hp) ----------------
__global__ void k_att(const unsigned int* __restrict__ hb32,   // bf16 pairs
                      const float* __restrict__ ws,
                      const float* __restrict__ wd, float* __restrict__ a_src,
                      float* __restrict__ a_dst) {
    int widx = blockIdx.x * 4 + (threadIdx.x >> 6);
    int lane = threadIdx.x & 63;
    if (widx >= N_NODES * NHEAD) return;
    int n = widx >> 2, h = widx & 3;
    // row = 512 bf16 per node = 256 dwords; head h occupies dwords [h*64, h*64+64)
    unsigned int u = hb32[(size_t)n * 256 + h * 64 + lane];
    float v0 = bf2f_lo(u), v1 = bf2f_hi(u);
    int c = 2 * lane;
    float s = v0 * ws[h * 128 + c] + v1 * ws[h * 128 + c + 1];
    float d = v0 * wd[h * 128 + c] + v1 * wd[h * 128 + c + 1];
    #pragma unroll
    for (int o = 32; o > 0; o >>= 1) { s += __shfl_down(s, o); d += __shfl_down(d, o); }
    if (lane == 0) { a_src[widx] = s; a_dst[widx] = d; }
}

// ---------------- fused aggregate + head-mean + LN + relu + residual ----------------
// One wave per node. Lane l: head = l>>4, owns 8 bf16 channels via one uint4 of the
// 1 KB row. Online-softmax state replicated per 16-lane group -> no cross-lane ops
// in the edge loop except the index broadcast.
__global__ __launch_bounds__(256) void k_agg(const uint4* __restrict__ hb4,
                                             const int* __restrict__ rowptr,
                                             const int* __restrict__ csr,
                                             const float* __restrict__ a_src,
                                             const float* __restrict__ a_dst,
                                             const float* __restrict__ bias,
                                             const float* __restrict__ lng,
                                             const float* __restrict__ lnb,
                                             float* __restrict__ h) {
    int wave = threadIdx.x >> 6;
    int lane = threadIdx.x & 63;
    int n = blockIdx.x * 4 + wave;
    if (n >= N_NODES) return;
    int hl = lane >> 4;                 // head of this lane
    int pos = lane & 15;                // position within head group
    int off = rowptr[n];
    int deg = rowptr[n + 1] - off;
    float adn = a_dst[n * 4 + hl];
    float m = -INFINITY, denom = 0.f;
    float o[8] = {};
    for (int base = 0; base < deg; base += 64) {
        int cnt = min(64, deg - base);
        int s = (lane < cnt) ? csr[off + base + lane] : 0;
        for (int i = 0; i < cnt; i++) {
            int si = __shfl(s, i);
            float t = a_src[si * 4 + hl] + adn;
            float e = t > 0.f ? t : 0.2f * t;
            float nm = fmaxf(m, e);
            float sc = __expf(m - nm);           // first edge: exp(-inf) = 0
            float p = __expf(e - nm);
            denom = denom * sc + p;
            uint4 u = hb4[(size_t)si * 64 + lane];
            o[0] = o[0] * sc + p * bf2f_lo(u.x);
            o[1] = o[1] * sc + p * bf2f_hi(u.x);
            o[2] = o[2] * sc + p * bf2f_lo(u.y);
            o[3] = o[3] * sc + p * bf2f_hi(u.y);
            o[4] = o[4] * sc + p * bf2f_lo(u.z);
            o[5] = o[5] * sc + p * bf2f_hi(u.z);
            o[6] = o[6] * sc + p * bf2f_lo(u.w);
            o[7] = o[7] * sc + p * bf2f_hi(u.w);
            m = nm;
        }
    }
    float inv = 1.f / (denom + 1e-16f);
    #pragma unroll
    for (int k = 0; k < 8; k++) o[k] *= inv;
    // head mean: sum the 4 head groups (lanes differing in bits 4,5)
    #pragma unroll
    for (int k = 0; k < 8; k++) {
        o[k] += __shfl_xor(o[k], 16);
        o[k] += __shfl_xor(o[k], 32);
    }
    // v_k = mean + bias for channels c = 8*pos + k (all 4 groups hold identical data)
    float v[8], sv = 0.f, sq = 0.f;
    #pragma unroll
    for (int k = 0; k < 8; k++) {
        float b = bias[8 * pos + k];
        v[k] = 0.25f * o[k] + b;
        sv += v[k]; sq += v[k] * v[k];
    }
    // LN stats over the 16 positions of the group
    #pragma unroll
    for (int d = 8; d > 0; d >>= 1) {
        sv += __shfl_xor(sv, d);
        sq += __shfl_xor(sq, d);
    }
    float mu = sv * (1.f / 128.f);
    float var = sq * (1.f / 128.f) - mu * mu;
    float rs = rsqrtf(var + LN_EPS);
    if (hl == 0) {                      // group 0 writes the 128 output channels
        float* hrow = h + (size_t)n * 128 + 8 * pos;
        float4 old0 = *(const float4*)(hrow);
        float4 old1 = *(const float4*)(hrow + 4);
        float r[8];
        #pragma unroll
        for (int k = 0; k < 8; k++) {
            float y = (v[k] - mu) * rs * lng[8 * pos + k] + lnb[8 * pos + k];
            r[k] = fmaxf(y, 0.f);
        }
        float4 w0 = make_float4(r[0] + old0.x, r[1] + old0.y, r[2] + old0.z, r[3] + old0.w);
        float4 w1 = make_float4(r[4] + old1.x, r[5] + old1.y, r[6] + old1.z, r[7] + old1.w);
        *(float4*)(hrow) = w0;
        *(float4*)(hrow + 4) = w1;
    }
}

// ---------------- graph mean pool (parallel, 3-phase) ----------------
#define POOL_CHUNK 32
__global__ __launch_bounds__(128) void k_pool_sum(const float* __restrict__ h,
                                                  const int* __restrict__ batch,
                                                  float* __restrict__ gout) {
    int n0 = blockIdx.x * POOL_CHUNK;
    int c = threadIdx.x;
    int nend = min(n0 + POOL_CHUNK, N_NODES);
    if (n0 >= N_NODES) return;
    int cur = batch[n0];
    float acc = 0.f;
    for (int n = n0; n < nend; n++) {
        int b = batch[n];                 // sorted: rarely changes within a chunk
        if (b != cur) {
            atomicAdd(&gout[cur * HIDDEN + c], acc);
            acc = 0.f; cur = b;
        }
        acc += h[(size_t)n * HIDDEN + c];
    }
    atomicAdd(&gout[cur * HIDDEN + c], acc);
}

__global__ void k_pool_div(const int* __restrict__ gstart, const int* __restrict__ gend,
                           float* __restrict__ gout) {
    int b = blockIdx.x, c = threadIdx.x;
    int cnt = gend[b] - gstart[b];
    gout[b * HIDDEN + c] *= 1.f / (float)max(cnt, 1);
}

extern "C" void kernel_launch(void* const* d_in, const int* in_sizes, int n_in,
                              void* d_out, int out_size, void* d_ws, size_t ws_size,
                              hipStream_t stream) {
    const float* x      = (const float*)d_in[0];
    const int*   ei     = (const int*)d_in[1];
    const int*   batch  = (const int*)d_in[2];
    const float* node_W = (const float*)d_in[3];
    const float* node_b = (const float*)d_in[4];
    const float* Ws     = (const float*)d_in[5];
    const float* att_s  = (const float*)d_in[6];
    const float* att_d  = (const float*)d_in[7];
    const float* biases = (const float*)d_in[8];
    const float* ln_g   = (const float*)d_in[9];
    const float* ln_b   = (const float*)d_in[10];

    float* out = (float*)d_out;
    float* h = out;                        // h lives in d_out[0 : N*128]
    float* gout = out + (size_t)N_NODES * HIDDEN;

    char* w = (char*)d_ws;
    auto carve = [&](size_t bytes) {
        void* p = (void*)w;
        w += (bytes + 255) & ~(size_t)255;
        return p;
    };
    int* rowptr  = (int*)carve((N_NODES + 1) * sizeof(int));
    int* cursor  = (int*)carve(N_NODES * sizeof(int));
    int* counts  = (int*)carve(N_NODES * sizeof(int));
    int* csr     = (int*)carve(E2 * sizeof(int));
    int* gstart  = (int*)carve(NB * sizeof(int));
    int* gend    = (int*)carve(NB * sizeof(int));
    float* a_src = (float*)carve((size_t)N_NODES * NHEAD * sizeof(float));
    float* a_dst = (float*)carve((size_t)N_NODES * NHEAD * sizeof(float));
    unsigned short* hb = (unsigned short*)carve((size_t)N_NODES * 512 * sizeof(unsigned short));

    k_init<<<(N_NODES + 255) / 256, 256, 0, stream>>>(counts, gstart, gend, gout);
    k_hist<<<(N_EDGES + 255) / 256, 256, 0, stream>>>(ei, counts);
    k_scan<<<1, 1024, 0, stream>>>(counts, rowptr, cursor);
    k_scatter<<<(E2 + 255) / 256, 256, 0, stream>>>(ei, cursor, csr);
    k_bounds<<<(N_NODES + 255) / 256, 256, 0, stream>>>(batch, gstart, gend);
    k_input<<<(N_NODES * HIDDEN + 255) / 256, 256, 0, stream>>>(x, node_W, node_b, h);

    for (int l = 0; l < 3; l++) {
        k_gemm<<<dim3(512 / BN, (N_NODES + BM - 1) / BM), 256, 0, stream>>>(
            h, Ws + (size_t)l * HIDDEN * 512, hb);
        k_att<<<N_NODES, 256, 0, stream>>>((const unsigned int*)hb,
                                           att_s + l * NHEAD * 128,
                                           att_d + l * NHEAD * 128, a_src, a_dst);
        k_agg<<<(N_NODES + 3) / 4, 256, 0, stream>>>((const uint4*)hb, rowptr, csr,
                                           a_src, a_dst,
                                           biases + l * HIDDEN, ln_g + l * HIDDEN,
                                           ln_b + l * HIDDEN, h);
    }
    k_pool_sum<<<(N_NODES + POOL_CHUNK - 1) / POOL_CHUNK, 128, 0, stream>>>(h, batch, gout);
    k_pool_div<<<NB, HIDDEN, 0, stream>>>(gstart, gend, gout);
}

// Round 6
// 290.348 us; speedup vs baseline: 1.8157x; 1.0443x over previous
//
#include <hip/hip_runtime.h>
#include <math.h>

#define N_NODES 10000
#define N_EDGES 160000
#define E2 (N_EDGES + N_NODES)
#define HIDDEN 128
#define NHEAD 4
#define NB 32
#define LN_EPS 1e-5f

typedef __attribute__((ext_vector_type(8))) short bf16x8;
typedef __attribute__((ext_vector_type(4))) float f32x4;

__device__ __forceinline__ unsigned short f2bf(float f) {
    unsigned int u = __float_as_uint(f);
    u += 0x7fffu + ((u >> 16) & 1u);       // RNE
    return (unsigned short)(u >> 16);
}
__device__ __forceinline__ float bf2f_lo(unsigned int u) { return __uint_as_float(u << 16); }
__device__ __forceinline__ float bf2f_hi(unsigned int u) { return __uint_as_float(u & 0xffff0000u); }

// ---------------- CSR build ----------------
__global__ void k_init(int* counts, int* gstart, int* gend, float* gout) {
    int i = blockIdx.x * blockDim.x + threadIdx.x;
    if (i < N_NODES) counts[i] = 1;             // self-loop
    if (i < NB) { gstart[i] = N_NODES; gend[i] = 0; }
    if (i < NB * HIDDEN) gout[i] = 0.f;          // pool accumulator (d_out is poisoned)
}

__global__ void k_hist(const int* __restrict__ ei, int* counts) {
    int e = blockIdx.x * blockDim.x + threadIdx.x;
    if (e < N_EDGES) atomicAdd(&counts[ei[N_EDGES + e]], 1);
}

__global__ void k_scan(const int* __restrict__ counts, int* rowptr, int* cursor) {
    __shared__ int sums[1024];
    int t = threadIdx.x;
    const int per = 10;                          // 1024*10 >= 10000
    int base = t * per;
    int loc[per];
    int s = 0;
    for (int i = 0; i < per; i++) {
        int idx = base + i;
        int v = (idx < N_NODES) ? counts[idx] : 0;
        loc[i] = s; s += v;
    }
    sums[t] = s;
    __syncthreads();
    for (int off = 1; off < 1024; off <<= 1) {
        int v = (t >= off) ? sums[t - off] : 0;
        __syncthreads();
        sums[t] += v;
        __syncthreads();
    }
    int prefix = (t > 0) ? sums[t - 1] : 0;
    for (int i = 0; i < per; i++) {
        int idx = base + i;
        if (idx < N_NODES) { int r = prefix + loc[i]; rowptr[idx] = r; cursor[idx] = r; }
    }
    if (t == 1023) rowptr[N_NODES] = sums[1023];
}

__global__ void k_scatter(const int* __restrict__ ei, int* cursor, int* csr_src) {
    int e = blockIdx.x * blockDim.x + threadIdx.x;
    if (e < N_EDGES) {
        int s = ei[e], d = ei[N_EDGES + e];
        int pos = atomicAdd(&cursor[d], 1);
        csr_src[pos] = s;
    } else if (e < E2) {
        int n = e - N_EDGES;
        int pos = atomicAdd(&cursor[n], 1);
        csr_src[pos] = n;
    }
}

// batch is sorted: detect graph boundaries locally, no atomics.
__global__ void k_bounds(const int* __restrict__ batch, int* gstart, int* gend) {
    int n = blockIdx.x * blockDim.x + threadIdx.x;
    if (n >= N_NODES) return;
    int b = batch[n];
    if (n == 0 || batch[n - 1] != b) gstart[b] = n;
    if (n == N_NODES - 1 || batch[n + 1] != b) gend[b] = n + 1;
}

// ---------------- weight prep: Btb[l][n][k] = bf16(Ws[l][k][n]) ----------------
__global__ void k_convB(const float* __restrict__ Ws, unsigned short* __restrict__ Btb) {
    int t = blockIdx.x * blockDim.x + threadIdx.x;
    if (t >= 3 * 512 * 128) return;
    int l = t >> 16, rem = t & 65535;
    int n = rem >> 7, k = rem & 127;
    Btb[t] = f2bf(Ws[l * 65536 + k * 512 + n]);
}

// ---------------- input projection: h = relu(x @ node_W + node_b), dual fp32+bf16 --
__global__ void k_input(const float* __restrict__ x, const float* __restrict__ W,
                        const float* __restrict__ b, float* __restrict__ h,
                        unsigned short* __restrict__ hb) {
    int t = blockIdx.x * blockDim.x + threadIdx.x;
    if (t >= N_NODES * HIDDEN) return;
    int n = t >> 7, c = t & 127;
    float s = b[c];
    #pragma unroll
    for (int k = 0; k < 5; k++) s += x[n * 5 + k] * W[k * HIDDEN + c];
    float r = fmaxf(s, 0.f);
    h[t] = r;
    hb[t] = f2bf(r);
}

// ---------------- MFMA bf16 GEMM: hp[M,512] = hb[M,128] @ Bt^T, no LDS ----------
// wave computes 16(M) x 64(N); block = 4 waves = 64 x 64; grid (8, 157).
__global__ __launch_bounds__(256) void k_gemm(const unsigned short* __restrict__ Ab,
                                              const unsigned short* __restrict__ Bt,
                                              unsigned short* __restrict__ Cb) {
    int wave = threadIdx.x >> 6, lane = threadIdx.x & 63;
    int q = lane >> 4, u = lane & 15;
    int mbase = blockIdx.y * 64 + wave * 16;
    int nbase = blockIdx.x * 64;
    int arow = mbase + u;
    if (arow > N_NODES - 1) arow = N_NODES - 1;   // clamp: OOB rows discarded on store
    bf16x8 a[4];
    #pragma unroll
    for (int k0 = 0; k0 < 4; k0++)
        a[k0] = *(const bf16x8*)(Ab + (size_t)arow * 128 + k0 * 32 + q * 8);
    f32x4 acc[4];
    #pragma unroll
    for (int nb = 0; nb < 4; nb++) acc[nb] = (f32x4){0.f, 0.f, 0.f, 0.f};
    #pragma unroll
    for (int nb = 0; nb < 4; nb++) {
        const unsigned short* bp = Bt + (size_t)(nbase + nb * 16 + u) * 128 + q * 8;
        #pragma unroll
        for (int k0 = 0; k0 < 4; k0++) {
            bf16x8 bfr = *(const bf16x8*)(bp + k0 * 32);
            acc[nb] = __builtin_amdgcn_mfma_f32_16x16x32_bf16(a[k0], bfr, acc[nb], 0, 0, 0);
        }
    }
    #pragma unroll
    for (int nb = 0; nb < 4; nb++) {
        int col = nbase + nb * 16 + u;
        #pragma unroll
        for (int r = 0; r < 4; r++) {
            int row = mbase + q * 4 + r;
            if (row < N_NODES) Cb[(size_t)row * 512 + col] = f2bf(acc[nb][r]);
        }
    }
}

// ---------------- attention scores: a_src/a_dst [N, H] (bf16 hp) ----------------
__global__ void k_att(const unsigned int* __restrict__ hb32,   // bf16 pairs
                      const float* __restrict__ ws,
                      const float* __restrict__ wd, float* __restrict__ a_src,
                      float* __restrict__ a_dst) {
    int widx = blockIdx.x * 4 + (threadIdx.x >> 6);
    int lane = threadIdx.x & 63;
    if (widx >= N_NODES * NHEAD) return;
    int n = widx >> 2, h = widx & 3;
    unsigned int u = hb32[(size_t)n * 256 + h * 64 + lane];
    float v0 = bf2f_lo(u), v1 = bf2f_hi(u);
    int c = 2 * lane;
    float s = v0 * ws[h * 128 + c] + v1 * ws[h * 128 + c + 1];
    float d = v0 * wd[h * 128 + c] + v1 * wd[h * 128 + c + 1];
    #pragma unroll
    for (int o = 32; o > 0; o >>= 1) { s += __shfl_down(s, o); d += __shfl_down(d, o); }
    if (lane == 0) { a_src[widx] = s; a_dst[widx] = d; }
}

// ---------------- fused aggregate + head-mean + LN + relu + residual ----------------
__global__ __launch_bounds__(256) void k_agg(const uint4* __restrict__ hb4,
                                             const int* __restrict__ rowptr,
                                             const int* __restrict__ csr,
                                             const float* __restrict__ a_src,
                                             const float* __restrict__ a_dst,
                                             const float* __restrict__ bias,
                                             const float* __restrict__ lng,
                                             const float* __restrict__ lnb,
                                             float* __restrict__ h,
                                             unsigned short* __restrict__ hbn) {
    int wave = threadIdx.x >> 6;
    int lane = threadIdx.x & 63;
    int n = blockIdx.x * 4 + wave;
    if (n >= N_NODES) return;
    int hl = lane >> 4;                 // head of this lane
    int pos = lane & 15;                // position within head group
    int off = rowptr[n];
    int deg = rowptr[n + 1] - off;
    float adn = a_dst[n * 4 + hl];
    float m = -INFINITY, denom = 0.f;
    float o[8] = {};
    for (int base = 0; base < deg; base += 64) {
        int cnt = min(64, deg - base);
        int s = (lane < cnt) ? csr[off + base + lane] : 0;
        for (int i = 0; i < cnt; i++) {
            int si = __shfl(s, i);
            float t = a_src[si * 4 + hl] + adn;
            float e = t > 0.f ? t : 0.2f * t;
            float nm = fmaxf(m, e);
            float sc = __expf(m - nm);           // first edge: exp(-inf) = 0
            float p = __expf(e - nm);
            denom = denom * sc + p;
            uint4 u = hb4[(size_t)si * 64 + lane];
            o[0] = o[0] * sc + p * bf2f_lo(u.x);
            o[1] = o[1] * sc + p * bf2f_hi(u.x);
            o[2] = o[2] * sc + p * bf2f_lo(u.y);
            o[3] = o[3] * sc + p * bf2f_hi(u.y);
            o[4] = o[4] * sc + p * bf2f_lo(u.z);
            o[5] = o[5] * sc + p * bf2f_hi(u.z);
            o[6] = o[6] * sc + p * bf2f_lo(u.w);
            o[7] = o[7] * sc + p * bf2f_hi(u.w);
            m = nm;
        }
    }
    float inv = 1.f / (denom + 1e-16f);
    #pragma unroll
    for (int k = 0; k < 8; k++) o[k] *= inv;
    #pragma unroll
    for (int k = 0; k < 8; k++) {
        o[k] += __shfl_xor(o[k], 16);
        o[k] += __shfl_xor(o[k], 32);
    }
    float v[8], sv = 0.f, sq = 0.f;
    #pragma unroll
    for (int k = 0; k < 8; k++) {
        float b = bias[8 * pos + k];
        v[k] = 0.25f * o[k] + b;
        sv += v[k]; sq += v[k] * v[k];
    }
    #pragma unroll
    for (int d = 8; d > 0; d >>= 1) {
        sv += __shfl_xor(sv, d);
        sq += __shfl_xor(sq, d);
    }
    float mu = sv * (1.f / 128.f);
    float var = sq * (1.f / 128.f) - mu * mu;
    float rs = rsqrtf(var + LN_EPS);
    if (hl == 0) {                      // group 0 writes the 128 output channels
        float* hrow = h + (size_t)n * 128 + 8 * pos;
        float4 old0 = *(const float4*)(hrow);
        float4 old1 = *(const float4*)(hrow + 4);
        float r[8];
        #pragma unroll
        for (int k = 0; k < 8; k++) {
            float y = (v[k] - mu) * rs * lng[8 * pos + k] + lnb[8 * pos + k];
            r[k] = fmaxf(y, 0.f);
        }
        float w[8] = {r[0] + old0.x, r[1] + old0.y, r[2] + old0.z, r[3] + old0.w,
                      r[4] + old1.x, r[5] + old1.y, r[6] + old1.z, r[7] + old1.w};
        *(float4*)(hrow) = make_float4(w[0], w[1], w[2], w[3]);
        *(float4*)(hrow + 4) = make_float4(w[4], w[5], w[6], w[7]);
        ushort4 p0, p1;
        p0.x = f2bf(w[0]); p0.y = f2bf(w[1]); p0.z = f2bf(w[2]); p0.w = f2bf(w[3]);
        p1.x = f2bf(w[4]); p1.y = f2bf(w[5]); p1.z = f2bf(w[6]); p1.w = f2bf(w[7]);
        unsigned short* hbrow = hbn + (size_t)n * 128 + 8 * pos;
        *(ushort4*)(hbrow) = p0;
        *(ushort4*)(hbrow + 4) = p1;
    }
}

// ---------------- graph mean pool (parallel, 3-phase) ----------------
#define POOL_CHUNK 32
__global__ __launch_bounds__(128) void k_pool_sum(const float* __restrict__ h,
                                                  const int* __restrict__ batch,
                                                  float* __restrict__ gout) {
    int n0 = blockIdx.x * POOL_CHUNK;
    int c = threadIdx.x;
    int nend = min(n0 + POOL_CHUNK, N_NODES);
    if (n0 >= N_NODES) return;
    int cur = batch[n0];
    float acc = 0.f;
    for (int n = n0; n < nend; n++) {
        int b = batch[n];                 // sorted: rarely changes within a chunk
        if (b != cur) {
            atomicAdd(&gout[cur * HIDDEN + c], acc);
            acc = 0.f; cur = b;
        }
        acc += h[(size_t)n * HIDDEN + c];
    }
    atomicAdd(&gout[cur * HIDDEN + c], acc);
}

__global__ void k_pool_div(const int* __restrict__ gstart, const int* __restrict__ gend,
                           float* __restrict__ gout) {
    int b = blockIdx.x, c = threadIdx.x;
    int cnt = gend[b] - gstart[b];
    gout[b * HIDDEN + c] *= 1.f / (float)max(cnt, 1);
}

extern "C" void kernel_launch(void* const* d_in, const int* in_sizes, int n_in,
                              void* d_out, int out_size, void* d_ws, size_t ws_size,
                              hipStream_t stream) {
    const float* x      = (const float*)d_in[0];
    const int*   ei     = (const int*)d_in[1];
    const int*   batch  = (const int*)d_in[2];
    const float* node_W = (const float*)d_in[3];
    const float* node_b = (const float*)d_in[4];
    const float* Ws     = (const float*)d_in[5];
    const float* att_s  = (const float*)d_in[6];
    const float* att_d  = (const float*)d_in[7];
    const float* biases = (const float*)d_in[8];
    const float* ln_g   = (const float*)d_in[9];
    const float* ln_b   = (const float*)d_in[10];

    float* out = (float*)d_out;
    float* h = out;                        // h lives in d_out[0 : N*128]
    float* gout = out + (size_t)N_NODES * HIDDEN;

    char* w = (char*)d_ws;
    auto carve = [&](size_t bytes) {
        void* p = (void*)w;
        w += (bytes + 255) & ~(size_t)255;
        return p;
    };
    int* rowptr  = (int*)carve((N_NODES + 1) * sizeof(int));
    int* cursor  = (int*)carve(N_NODES * sizeof(int));
    int* counts  = (int*)carve(N_NODES * sizeof(int));
    int* csr     = (int*)carve(E2 * sizeof(int));
    int* gstart  = (int*)carve(NB * sizeof(int));
    int* gend    = (int*)carve(NB * sizeof(int));
    float* a_src = (float*)carve((size_t)N_NODES * NHEAD * sizeof(float));
    float* a_dst = (float*)carve((size_t)N_NODES * NHEAD * sizeof(float));
    unsigned short* hb  = (unsigned short*)carve((size_t)N_NODES * 512 * sizeof(unsigned short));
    unsigned short* hbx = (unsigned short*)carve((size_t)N_NODES * HIDDEN * sizeof(unsigned short));
    unsigned short* Btb = (unsigned short*)carve((size_t)3 * 512 * 128 * sizeof(unsigned short));

    k_init<<<(N_NODES + 255) / 256, 256, 0, stream>>>(counts, gstart, gend, gout);
    k_hist<<<(N_EDGES + 255) / 256, 256, 0, stream>>>(ei, counts);
    k_scan<<<1, 1024, 0, stream>>>(counts, rowptr, cursor);
    k_scatter<<<(E2 + 255) / 256, 256, 0, stream>>>(ei, cursor, csr);
    k_bounds<<<(N_NODES + 255) / 256, 256, 0, stream>>>(batch, gstart, gend);
    k_convB<<<(3 * 512 * 128 + 255) / 256, 256, 0, stream>>>(Ws, Btb);
    k_input<<<(N_NODES * HIDDEN + 255) / 256, 256, 0, stream>>>(x, node_W, node_b, h, hbx);

    for (int l = 0; l < 3; l++) {
        k_gemm<<<dim3(8, (N_NODES + 63) / 64), 256, 0, stream>>>(
            hbx, Btb + (size_t)l * 512 * 128, hb);
        k_att<<<N_NODES, 256, 0, stream>>>((const unsigned int*)hb,
                                           att_s + l * NHEAD * 128,
                                           att_d + l * NHEAD * 128, a_src, a_dst);
        k_agg<<<(N_NODES + 3) / 4, 256, 0, stream>>>((const uint4*)hb, rowptr, csr,
                                           a_src, a_dst,
                                           biases + l * HIDDEN, ln_g + l * HIDDEN,
                                           ln_b + l * HIDDEN, h, hbx);
    }
    k_pool_sum<<<(N_NODES + POOL_CHUNK - 1) / POOL_CHUNK, 128, 0, stream>>>(h, batch, gout);
    k_pool_div<<<NB, HIDDEN, 0, stream>>>(gstart, gend, gout);
}

// Round 7
// 272.581 us; speedup vs baseline: 1.9341x; 1.0652x over previous
//
#include <hip/hip_runtime.h>
#include <math.h>

#define N_NODES 10000
#define N_EDGES 160000
#define E2 (N_EDGES + N_NODES)
#define HIDDEN 128
#define NHEAD 4
#define NB 32
#define LN_EPS 1e-5f

// flat-tid region boundaries for k_pre
#define T_INPUT (N_NODES * HIDDEN)                 // 1,280,000
#define T_HIST  (T_INPUT + N_EDGES)                // +160,000
#define T_CONV  (T_HIST + 3 * 512 * 128)           // +196,608
#define T_BOUND (T_CONV + N_NODES)                 // +10,000
#define T_TOTAL T_BOUND

typedef __attribute__((ext_vector_type(8))) short bf16x8;
typedef __attribute__((ext_vector_type(4))) float f32x4;

__device__ __forceinline__ unsigned short f2bf(float f) {
    unsigned int u = __float_as_uint(f);
    u += 0x7fffu + ((u >> 16) & 1u);       // RNE
    return (unsigned short)(u >> 16);
}
__device__ __forceinline__ float bf2f_lo(unsigned int u) { return __uint_as_float(u << 16); }
__device__ __forceinline__ float bf2f_hi(unsigned int u) { return __uint_as_float(u & 0xffff0000u); }

// ---------------- fused preamble: input proj + edge hist + weight conv + bounds ----
// counts and gout are zeroed by hipMemsetAsync before this kernel.
__global__ __launch_bounds__(256) void k_pre(const float* __restrict__ x,
                                             const float* __restrict__ W,
                                             const float* __restrict__ b,
                                             const int* __restrict__ ei,
                                             const int* __restrict__ batch,
                                             const float* __restrict__ Ws,
                                             float* __restrict__ h,
                                             unsigned short* __restrict__ hb,
                                             int* counts, int* gstart, int* gend,
                                             unsigned short* __restrict__ Btb) {
    int t = blockIdx.x * blockDim.x + threadIdx.x;
    if (t < T_INPUT) {
        int n = t >> 7, c = t & 127;
        float s = b[c];
        #pragma unroll
        for (int k = 0; k < 5; k++) s += x[n * 5 + k] * W[k * HIDDEN + c];
        float r = fmaxf(s, 0.f);
        h[t] = r;
        hb[t] = f2bf(r);
    } else if (t < T_HIST) {
        int e = t - T_INPUT;
        atomicAdd(&counts[ei[N_EDGES + e]], 1);
    } else if (t < T_CONV) {
        int i = t - T_HIST;
        int l = i >> 16, rem = i & 65535;
        int n = rem >> 7, k = rem & 127;
        Btb[i] = f2bf(Ws[l * 65536 + k * 512 + n]);
    } else if (t < T_BOUND) {
        int n = t - T_CONV;
        int bb = batch[n];
        if (n == 0 || batch[n - 1] != bb) gstart[bb] = n;
        if (n == N_NODES - 1 || batch[n + 1] != bb) gend[bb] = n + 1;
    }
}

// ---------------- prefix scan (adds +1 self-loop per node) ----------------
__global__ void k_scan(const int* __restrict__ counts, int* rowptr, int* cursor) {
    __shared__ int sums[1024];
    int t = threadIdx.x;
    const int per = 10;
    int base = t * per;
    int loc[per];
    int s = 0;
    for (int i = 0; i < per; i++) {
        int idx = base + i;
        int v = (idx < N_NODES) ? counts[idx] + 1 : 0;   // +1 = self-loop
        loc[i] = s; s += v;
    }
    sums[t] = s;
    __syncthreads();
    for (int off = 1; off < 1024; off <<= 1) {
        int v = (t >= off) ? sums[t - off] : 0;
        __syncthreads();
        sums[t] += v;
        __syncthreads();
    }
    int prefix = (t > 0) ? sums[t - 1] : 0;
    for (int i = 0; i < per; i++) {
        int idx = base + i;
        if (idx < N_NODES) { int r = prefix + loc[i]; rowptr[idx] = r; cursor[idx] = r; }
    }
    if (t == 1023) rowptr[N_NODES] = sums[1023];
}

__global__ void k_scatter(const int* __restrict__ ei, int* cursor, int* csr_src) {
    int e = blockIdx.x * blockDim.x + threadIdx.x;
    if (e < N_EDGES) {
        int s = ei[e], d = ei[N_EDGES + e];
        int pos = atomicAdd(&cursor[d], 1);
        csr_src[pos] = s;
    } else if (e < E2) {
        int n = e - N_EDGES;
        int pos = atomicAdd(&cursor[n], 1);
        csr_src[pos] = n;
    }
}

// ---------------- MFMA GEMM + fused attention scores -------------------------
// Block = 4 waves = 32 rows x 128 cols (one full head). Grid (4 heads, 313).
// Wave w: rows mbase+16*(w&1), cols h*128 + 64*(w>>1).
__global__ __launch_bounds__(256) void k_gemm_att(const unsigned short* __restrict__ Ab,
                                                  const unsigned short* __restrict__ Bt,
                                                  const float* __restrict__ ws,
                                                  const float* __restrict__ wd,
                                                  unsigned short* __restrict__ Cb,
                                                  float* __restrict__ a_src,
                                                  float* __restrict__ a_dst) {
    int wave = threadIdx.x >> 6, lane = threadIdx.x & 63;
    int q = lane >> 4, u = lane & 15;
    int h = blockIdx.x;
    int rowgrp = wave & 1, colhalf = wave >> 1;
    int mbase = blockIdx.y * 32 + rowgrp * 16;
    int colbase = h * 128 + colhalf * 64;
    int arow = mbase + u;
    if (arow > N_NODES - 1) arow = N_NODES - 1;   // clamp; OOB stores guarded
    bf16x8 a[4];
    #pragma unroll
    for (int k0 = 0; k0 < 4; k0++)
        a[k0] = *(const bf16x8*)(Ab + (size_t)arow * 128 + k0 * 32 + q * 8);
    f32x4 acc[4];
    #pragma unroll
    for (int nb = 0; nb < 4; nb++) acc[nb] = (f32x4){0.f, 0.f, 0.f, 0.f};
    #pragma unroll
    for (int nb = 0; nb < 4; nb++) {
        const unsigned short* bp = Bt + (size_t)(colbase + nb * 16 + u) * 128 + q * 8;
        #pragma unroll
        for (int k0 = 0; k0 < 4; k0++) {
            bf16x8 bfr = *(const bf16x8*)(bp + k0 * 32);
            acc[nb] = __builtin_amdgcn_mfma_f32_16x16x32_bf16(a[k0], bfr, acc[nb], 0, 0, 0);
        }
    }
    // store hp (bf16)
    #pragma unroll
    for (int nb = 0; nb < 4; nb++) {
        int col = colbase + nb * 16 + u;
        #pragma unroll
        for (int r = 0; r < 4; r++) {
            int row = mbase + q * 4 + r;
            if (row < N_NODES) Cb[(size_t)row * 512 + col] = f2bf(acc[nb][r]);
        }
    }
    // attention partial dots (from fp32 accumulators)
    float ps[4] = {}, pd[4] = {};
    #pragma unroll
    for (int nb = 0; nb < 4; nb++) {
        int cl = colhalf * 64 + nb * 16 + u;          // channel within head
        float wsv = ws[h * 128 + cl], wdv = wd[h * 128 + cl];
        #pragma unroll
        for (int r = 0; r < 4; r++) { ps[r] += acc[nb][r] * wsv; pd[r] += acc[nb][r] * wdv; }
    }
    #pragma unroll
    for (int d = 1; d < 16; d <<= 1) {
        #pragma unroll
        for (int r = 0; r < 4; r++) {
            ps[r] += __shfl_xor(ps[r], d);
            pd[r] += __shfl_xor(pd[r], d);
        }
    }
    __shared__ float ls[2][2][16], ldd[2][2][16];
    if (u == 0) {
        #pragma unroll
        for (int r = 0; r < 4; r++) {
            ls[rowgrp][colhalf][q * 4 + r] = ps[r];
            ldd[rowgrp][colhalf][q * 4 + r] = pd[r];
        }
    }
    __syncthreads();
    if (colhalf == 0 && lane < 16) {
        int row = mbase + lane;
        if (row < N_NODES) {
            a_src[row * 4 + h] = ls[rowgrp][0][lane] + ls[rowgrp][1][lane];
            a_dst[row * 4 + h] = ldd[rowgrp][0][lane] + ldd[rowgrp][1][lane];
        }
    }
}

// ---------------- fused aggregate + head-mean + LN + relu + residual ----------------
__global__ __launch_bounds__(256) void k_agg(const uint4* __restrict__ hb4,
                                             const int* __restrict__ rowptr,
                                             const int* __restrict__ csr,
                                             const float* __restrict__ a_src,
                                             const float* __restrict__ a_dst,
                                             const float* __restrict__ bias,
                                             const float* __restrict__ lng,
                                             const float* __restrict__ lnb,
                                             float* __restrict__ h,
                                             unsigned short* __restrict__ hbn) {
    int wave = threadIdx.x >> 6;
    int lane = threadIdx.x & 63;
    int n = blockIdx.x * 4 + wave;
    if (n >= N_NODES) return;
    int hl = lane >> 4;
    int pos = lane & 15;
    int off = rowptr[n];
    int deg = rowptr[n + 1] - off;
    float adn = a_dst[n * 4 + hl];
    float m = -INFINITY, denom = 0.f;
    float o[8] = {};
    for (int base = 0; base < deg; base += 64) {
        int cnt = min(64, deg - base);
        int s = (lane < cnt) ? csr[off + base + lane] : 0;
        for (int i = 0; i < cnt; i++) {
            int si = __shfl(s, i);
            float t = a_src[si * 4 + hl] + adn;
            float e = t > 0.f ? t : 0.2f * t;
            float nm = fmaxf(m, e);
            float sc = __expf(m - nm);
            float p = __expf(e - nm);
            denom = denom * sc + p;
            uint4 u = hb4[(size_t)si * 64 + lane];
            o[0] = o[0] * sc + p * bf2f_lo(u.x);
            o[1] = o[1] * sc + p * bf2f_hi(u.x);
            o[2] = o[2] * sc + p * bf2f_lo(u.y);
            o[3] = o[3] * sc + p * bf2f_hi(u.y);
            o[4] = o[4] * sc + p * bf2f_lo(u.z);
            o[5] = o[5] * sc + p * bf2f_hi(u.z);
            o[6] = o[6] * sc + p * bf2f_lo(u.w);
            o[7] = o[7] * sc + p * bf2f_hi(u.w);
            m = nm;
        }
    }
    float inv = 1.f / (denom + 1e-16f);
    #pragma unroll
    for (int k = 0; k < 8; k++) o[k] *= inv;
    #pragma unroll
    for (int k = 0; k < 8; k++) {
        o[k] += __shfl_xor(o[k], 16);
        o[k] += __shfl_xor(o[k], 32);
    }
    float v[8], sv = 0.f, sq = 0.f;
    #pragma unroll
    for (int k = 0; k < 8; k++) {
        float b = bias[8 * pos + k];
        v[k] = 0.25f * o[k] + b;
        sv += v[k]; sq += v[k] * v[k];
    }
    #pragma unroll
    for (int d = 8; d > 0; d >>= 1) {
        sv += __shfl_xor(sv, d);
        sq += __shfl_xor(sq, d);
    }
    float mu = sv * (1.f / 128.f);
    float var = sq * (1.f / 128.f) - mu * mu;
    float rs = rsqrtf(var + LN_EPS);
    if (hl == 0) {
        float* hrow = h + (size_t)n * 128 + 8 * pos;
        float4 old0 = *(const float4*)(hrow);
        float4 old1 = *(const float4*)(hrow + 4);
        float r[8];
        #pragma unroll
        for (int k = 0; k < 8; k++) {
            float y = (v[k] - mu) * rs * lng[8 * pos + k] + lnb[8 * pos + k];
            r[k] = fmaxf(y, 0.f);
        }
        float w[8] = {r[0] + old0.x, r[1] + old0.y, r[2] + old0.z, r[3] + old0.w,
                      r[4] + old1.x, r[5] + old1.y, r[6] + old1.z, r[7] + old1.w};
        *(float4*)(hrow) = make_float4(w[0], w[1], w[2], w[3]);
        *(float4*)(hrow + 4) = make_float4(w[4], w[5], w[6], w[7]);
        ushort4 p0, p1;
        p0.x = f2bf(w[0]); p0.y = f2bf(w[1]); p0.z = f2bf(w[2]); p0.w = f2bf(w[3]);
        p1.x = f2bf(w[4]); p1.y = f2bf(w[5]); p1.z = f2bf(w[6]); p1.w = f2bf(w[7]);
        unsigned short* hbrow = hbn + (size_t)n * 128 + 8 * pos;
        *(ushort4*)(hbrow) = p0;
        *(ushort4*)(hbrow + 4) = p1;
    }
}

// ---------------- graph mean pool (atomic partial sums, pre-divided) ------------
#define POOL_CHUNK 32
__global__ __launch_bounds__(128) void k_pool_sum(const float* __restrict__ h,
                                                  const int* __restrict__ batch,
                                                  const int* __restrict__ gstart,
                                                  const int* __restrict__ gend,
                                                  float* __restrict__ gout) {
    int n0 = blockIdx.x * POOL_CHUNK;
    int c = threadIdx.x;
    int nend = min(n0 + POOL_CHUNK, N_NODES);
    if (n0 >= N_NODES) return;
    int cur = batch[n0];
    float acc = 0.f;
    for (int n = n0; n < nend; n++) {
        int b = batch[n];
        if (b != cur) {
            float inv = 1.f / (float)max(gend[cur] - gstart[cur], 1);
            atomicAdd(&gout[cur * HIDDEN + c], acc * inv);
            acc = 0.f; cur = b;
        }
        acc += h[(size_t)n * HIDDEN + c];
    }
    float inv = 1.f / (float)max(gend[cur] - gstart[cur], 1);
    atomicAdd(&gout[cur * HIDDEN + c], acc * inv);
}

extern "C" void kernel_launch(void* const* d_in, const int* in_sizes, int n_in,
                              void* d_out, int out_size, void* d_ws, size_t ws_size,
                              hipStream_t stream) {
    const float* x      = (const float*)d_in[0];
    const int*   ei     = (const int*)d_in[1];
    const int*   batch  = (const int*)d_in[2];
    const float* node_W = (const float*)d_in[3];
    const float* node_b = (const float*)d_in[4];
    const float* Ws     = (const float*)d_in[5];
    const float* att_s  = (const float*)d_in[6];
    const float* att_d  = (const float*)d_in[7];
    const float* biases = (const float*)d_in[8];
    const float* ln_g   = (const float*)d_in[9];
    const float* ln_b   = (const float*)d_in[10];

    float* out = (float*)d_out;
    float* h = out;                        // h lives in d_out[0 : N*128]
    float* gout = out + (size_t)N_NODES * HIDDEN;

    char* w = (char*)d_ws;
    auto carve = [&](size_t bytes) {
        void* p = (void*)w;
        w += (bytes + 255) & ~(size_t)255;
        return p;
    };
    int* rowptr  = (int*)carve((N_NODES + 1) * sizeof(int));
    int* cursor  = (int*)carve(N_NODES * sizeof(int));
    int* counts  = (int*)carve(N_NODES * sizeof(int));
    int* csr     = (int*)carve(E2 * sizeof(int));
    int* gstart  = (int*)carve(NB * sizeof(int));
    int* gend    = (int*)carve(NB * sizeof(int));
    float* a_src = (float*)carve((size_t)N_NODES * NHEAD * sizeof(float));
    float* a_dst = (float*)carve((size_t)N_NODES * NHEAD * sizeof(float));
    unsigned short* hb  = (unsigned short*)carve((size_t)N_NODES * 512 * sizeof(unsigned short));
    unsigned short* hbx = (unsigned short*)carve((size_t)N_NODES * HIDDEN * sizeof(unsigned short));
    unsigned short* Btb = (unsigned short*)carve((size_t)3 * 512 * 128 * sizeof(unsigned short));

    hipMemsetAsync(counts, 0, N_NODES * sizeof(int), stream);
    hipMemsetAsync(gout, 0, NB * HIDDEN * sizeof(float), stream);

    k_pre<<<(T_TOTAL + 255) / 256, 256, 0, stream>>>(x, node_W, node_b, ei, batch, Ws,
                                                     h, hbx, counts, gstart, gend, Btb);
    k_scan<<<1, 1024, 0, stream>>>(counts, rowptr, cursor);
    k_scatter<<<(E2 + 255) / 256, 256, 0, stream>>>(ei, cursor, csr);

    for (int l = 0; l < 3; l++) {
        k_gemm_att<<<dim3(4, (N_NODES + 31) / 32), 256, 0, stream>>>(
            hbx, Btb + (size_t)l * 512 * 128,
            att_s + l * NHEAD * 128, att_d + l * NHEAD * 128,
            hb, a_src, a_dst);
        k_agg<<<(N_NODES + 3) / 4, 256, 0, stream>>>((const uint4*)hb, rowptr, csr,
                                           a_src, a_dst,
                                           biases + l * HIDDEN, ln_g + l * HIDDEN,
                                           ln_b + l * HIDDEN, h, hbx);
    }
    k_pool_sum<<<(N_NODES + POOL_CHUNK - 1) / POOL_CHUNK, 128, 0, stream>>>(
        h, batch, gstart, gend, gout);
}